// Round 24
// baseline (170.421 us; speedup 1.0000x reference)
//
#include <hip/hip_runtime.h>

constexpr int D_IN = 20;   // input feature dim
constexpr int HP   = 16;   // projection dim
constexpr int K    = 6;    // neighbors
constexpr int SAMP = 512;  // threshold sample size
constexpr int CAPL = 384;  // per-row LDS hit-buffer capacity (mean ~96)
constexpr int CIN  = 128;  // per-row in-edge slots
constexpr float MARGIN = 0.02f;  // covers bf16-vs-fp32 dot error

typedef __attribute__((ext_vector_type(8))) short bf16x8;
typedef __attribute__((ext_vector_type(4))) float f32x4;

// Sequential fmaf dot — MUST be bit-identical across thresh/final.
__device__ __forceinline__ float dot16_seq(const float4* q, const float4* c) {
  float s = 0.f;
#pragma unroll
  for (int m = 0; m < 4; ++m) {
    s = fmaf(q[m].x, c[m].x, s);
    s = fmaf(q[m].y, c[m].y, s);
    s = fmaf(q[m].z, c[m].z, s);
    s = fmaf(q[m].w, c[m].w, s);
  }
  return s;
}

// round-to-nearest-even f32 -> bf16 bits
__device__ __forceinline__ short f2bf(float f) {
  unsigned u = __float_as_uint(f);
  unsigned r = (u + 0x7fffu + ((u >> 16) & 1u)) >> 16;
  return (short)r;
}

__device__ __forceinline__ float dinv_of(float own, float ins) {
  float rs = 0.5f * (own + ins);
  float rn = 1.f / (rs + 1e-8f);
  return rsqrtf(fmaxf(1.f + rs * rn, 1e-12f));
}

// ---- projection + row-normalize + bf16 copy + XW0 + counter zeroing ----
__global__ void k_proj(const float* __restrict__ x, const float* __restrict__ Wp,
                       const float* __restrict__ bp, const float* __restrict__ gw0,
                       float* __restrict__ hn, short* __restrict__ hnb,
                       float* __restrict__ XW0,
                       float* __restrict__ insum, int* __restrict__ indeg, int N) {
  int i = blockIdx.x * blockDim.x + threadIdx.x;
  if (i >= N) return;
  insum[i] = 0.f; indeg[i] = 0;
  float xr[D_IN];
#pragma unroll
  for (int d = 0; d < D_IN; ++d) xr[d] = x[i*D_IN + d];
  float hv[HP];
  float nrm2 = 0.f;
#pragma unroll
  for (int h = 0; h < HP; ++h) {
    float a = bp[h];
#pragma unroll
    for (int d = 0; d < D_IN; ++d) a += xr[d] * Wp[d*HP + h];
    hv[h] = a;
    nrm2 += a * a;
  }
  float inv = 1.f / fmaxf(sqrtf(nrm2), 1e-12f);
#pragma unroll
  for (int h = 0; h < HP; ++h) {
    float v = hv[h] * inv;
    hn[i*HP + h] = v;
    hnb[(size_t)i*32 + h] = f2bf(v);
  }
#pragma unroll
  for (int h = 0; h < HP; ++h) hnb[(size_t)i*32 + 16 + h] = 0;
#pragma unroll
  for (int oc = 0; oc < 32; ++oc) {
    float a = 0.f;
#pragma unroll
    for (int d = 0; d < D_IN; ++d) a += xr[d] * gw0[d*32 + oc];
    XW0[(size_t)i*32 + oc] = a;
  }
}

// ---------------- per-lane top-6 in NAMED registers ----
struct Top6 { float v0,v1,v2,v3,v4,v5; int i0,i1,i2,i3,i4,i5; };

__device__ __forceinline__ void t6_init(Top6& t) {
  t.v0=t.v1=t.v2=t.v3=t.v4=t.v5=-1e30f;
  t.i0=t.i1=t.i2=t.i3=t.i4=t.i5=-1;
}

#define T6_SWAP(a,b,ia,ib) { float tv=a; a=b; b=tv; int ti=ia; ia=ib; ib=ti; }

__device__ __forceinline__ void t6_insert(Top6& t, float s, int c) {
  if (s > t.v5) {
    t.v5 = s; t.i5 = c;
    if (t.v5 > t.v4) { T6_SWAP(t.v4, t.v5, t.i4, t.i5); }
    if (t.v4 > t.v3) { T6_SWAP(t.v3, t.v4, t.i3, t.i4); }
    if (t.v3 > t.v2) { T6_SWAP(t.v2, t.v3, t.i2, t.i3); }
    if (t.v2 > t.v1) { T6_SWAP(t.v1, t.v2, t.i1, t.i2); }
    if (t.v1 > t.v0) { T6_SWAP(t.v0, t.v1, t.i0, t.i1); }
  }
}

__device__ __forceinline__ void t6_best(const Top6& t, float& cv, int& ci) {
  cv = t.v0; ci = t.i0;
  if (t.v1 > cv || (t.v1 == cv && (unsigned)t.i1 < (unsigned)ci)) { cv = t.v1; ci = t.i1; }
  if (t.v2 > cv || (t.v2 == cv && (unsigned)t.i2 < (unsigned)ci)) { cv = t.v2; ci = t.i2; }
  if (t.v3 > cv || (t.v3 == cv && (unsigned)t.i3 < (unsigned)ci)) { cv = t.v3; ci = t.i3; }
  if (t.v4 > cv || (t.v4 == cv && (unsigned)t.i4 < (unsigned)ci)) { cv = t.v4; ci = t.i4; }
  if (t.v5 > cv || (t.v5 == cv && (unsigned)t.i5 < (unsigned)ci)) { cv = t.v5; ci = t.i5; }
}

__device__ __forceinline__ void t6_consume(Top6& t, int mi) {
  if (t.i0 == mi) t.v0 = -1e30f;
  if (t.i1 == mi) t.v1 = -1e30f;
  if (t.i2 == mi) t.v2 = -1e30f;
  if (t.i3 == mi) t.v3 = -1e30f;
  if (t.i4 == mi) t.v4 = -1e30f;
  if (t.i5 == mi) t.v5 = -1e30f;
}

// ---- FUSED: per-row threshold + MFMA scan (LDS hit buffers) + exact top-6 ----
// 512 blocks x 512 threads (8 waves). 512-thread blocks keep the allocator's
// sane VGPR heuristic (R23's 1024-thread block got VGPR=32 -> remat storm).
// Phase 1: wave w -> tau of rows r0+2w, r0+2w+1 (exact fp32 over SAMP sample).
// Phase 2: wave w MFMA-scans candidates [w*1024, w*1024+1024) for all 16 rows.
// Phase 3: wave w -> exact fp32 top-6 of rows r0+2w, r0+2w+1 from LDS hits.
__global__ __launch_bounds__(512, 4) void k_scanfin(
    const float* __restrict__ hn, const short* __restrict__ hnb,
    float* __restrict__ evals, int* __restrict__ eidx,
    float* __restrict__ ownsum, float* insum, int* indeg,
    unsigned short* __restrict__ incol, float* __restrict__ inval, int N) {
  __shared__ unsigned short hbuf[16][CAPL];   // 12 KB
  __shared__ int cntl[16];
  __shared__ float tau_s[16];
  int tid = threadIdx.x;
  int wave = tid >> 6, lane = tid & 63;
  int r0 = blockIdx.x * 16;
  const float4* hn4 = (const float4*)hn;

  if (tid < 16) cntl[tid] = 0;

  // ---- phase 1: threshold, 2 rows per wave ----
  for (int r = 0; r < 2; ++r) {
    int row = r0 + wave*2 + r;
    float4 q[4];
#pragma unroll
    for (int m = 0; m < 4; ++m) q[m] = hn4[(size_t)row*4 + m];
    Top6 t; t6_init(t);
    for (int k = 0; k < SAMP/64; ++k) {
      int c = lane + 64*k;
      if (c != row) {
        float4 cv[4];
#pragma unroll
        for (int m = 0; m < 4; ++m) cv[m] = hn4[(size_t)c*4 + m];
        float s = dot16_seq(q, cv);
        t6_insert(t, s, c);
      }
    }
    float last = -1e30f;
    for (int sel = 0; sel < K; ++sel) {
      float cv; int ci;
      t6_best(t, cv, ci);
      float mv = cv; int mi = ci;
#pragma unroll
      for (int m = 1; m < 64; m <<= 1) {
        float ov = __shfl_xor(mv, m);
        int   oi = __shfl_xor(mi, m);
        if (ov > mv || (ov == mv && (unsigned)oi < (unsigned)mi)) { mv = ov; mi = oi; }
      }
      t6_consume(t, mi);
      last = mv;
    }
    if (lane == 0) tau_s[wave*2 + r] = last;
  }
  __syncthreads();

  // ---- phase 2: MFMA scan into LDS hit buffers ----
  {
    int half = lane >> 4;            // 0..3
    int l16  = lane & 15;
    bf16x8 a = *(const bf16x8*)(hnb + (size_t)(r0 + l16)*32 + half*8);
    float tm0 = tau_s[half*4+0] - MARGIN, tm1 = tau_s[half*4+1] - MARGIN,
          tm2 = tau_s[half*4+2] - MARGIN, tm3 = tau_s[half*4+3] - MARGIN;
    f32x4 zero = {0.f, 0.f, 0.f, 0.f};
    const int SPANW = N / 8;         // 1024 cands per wave
    int jb0 = wave * SPANW;

#define APPB(R, COND)                                                        \
    {                                                                        \
      unsigned long long mr = __ballot(COND);                                \
      if (l16 == 0) {                                                        \
        unsigned mask = (unsigned)(mr >> (16*half)) & 0xFFFFu;               \
        if (mask) {                                                          \
          int rl = 4*half + (R);                                             \
          int pos = atomicAdd(&cntl[rl], __popc(mask));                      \
          unsigned mm = mask;                                                \
          while (mm) {                                                       \
            int bx = __ffs(mm) - 1; mm &= mm - 1;                            \
            if (pos < CAPL) hbuf[rl][pos] = (unsigned short)(jb + bx);       \
            ++pos;                                                           \
          }                                                                  \
        }                                                                    \
      }                                                                      \
    }

#pragma unroll 4
    for (int jt = 0; jt < SPANW; jt += 16) {
      int jb = jb0 + jt;
      bf16x8 b = *(const bf16x8*)(hnb + (size_t)(jb + l16)*32 + half*8);
      f32x4 d = __builtin_amdgcn_mfma_f32_16x16x32_bf16(a, b, zero, 0, 0, 0);
      bool h0 = d[0] >= tm0, h1 = d[1] >= tm1, h2 = d[2] >= tm2, h3 = d[3] >= tm3;
      if (__any(h0 | h1 | h2 | h3)) {
        APPB(0, h0) APPB(1, h1) APPB(2, h2) APPB(3, h3)
      }
    }
#undef APPB
  }
  __syncthreads();

  // ---- phase 3: exact fp32 top-6 from LDS hit list, 2 rows per wave ----
  for (int r = 0; r < 2; ++r) {
    int rl = wave*2 + r;
    int row = r0 + rl;
    int n = min(cntl[rl], CAPL);
    float4 q[4];
#pragma unroll
    for (int m = 0; m < 4; ++m) q[m] = hn4[(size_t)row*4 + m];
    Top6 t; t6_init(t);
    for (int e = lane; e < n; e += 64) {
      int j = hbuf[rl][e];
      if (j != row) {
        float4 cv[4];
#pragma unroll
        for (int m = 0; m < 4; ++m) cv[m] = hn4[(size_t)j*4 + m];
        float sc = dot16_seq(q, cv);
        t6_insert(t, sc, j);
      }
    }
    float osum = 0.f;
    for (int sel = 0; sel < K; ++sel) {
      float cv; int ci;
      t6_best(t, cv, ci);
      float mv = cv; int mi = ci;
#pragma unroll
      for (int m = 1; m < 64; m <<= 1) {
        float ov = __shfl_xor(mv, m);
        int   oi = __shfl_xor(mi, m);
        if (ov > mv || (ov == mv && (unsigned)oi < (unsigned)mi)) { mv = ov; mi = oi; }
      }
      t6_consume(t, mi);
      if (lane == 0) {
        evals[row*K + sel] = mv;
        eidx [row*K + sel] = mi;
        osum += mv;
        atomicAdd(&insum[mi], mv);
        int pos = atomicAdd(&indeg[mi], 1);
        if (pos < CIN) {
          incol[(size_t)mi*CIN + pos] = (unsigned short)row;
          inval[(size_t)mi*CIN + pos] = mv;
        }
      }
    }
    if (lane == 0) ownsum[row] = osum;
  }
}

// ---- DOUT=32 layer: GCN + LN + ReLU + MLP residual, 2 rows/wave.
// SCALED: XWsrc already carries dinv_j -> per-edge coef is cc*v.
// Epilogue writes XWnext PRE-SCALED by dinv_row.
template<int DIN, int NEXTD, bool SCALED>
__global__ __launch_bounds__(256) void k_gpost32(
    const float* __restrict__ XWsrc,
    const int* __restrict__ eidx, const float* __restrict__ evals,
    const unsigned short* __restrict__ incol, const float* __restrict__ inval,
    const int* __restrict__ indeg,
    const float* __restrict__ ownsum, const float* __restrict__ insum,
    const float* __restrict__ gb, const float* __restrict__ lg, const float* __restrict__ lb,
    const float* __restrict__ hprev,
    const float* __restrict__ w0, const float* __restrict__ b0,
    const float* __restrict__ w1, const float* __restrict__ b1,
    const float* __restrict__ Wnext, float* __restrict__ XWnext,
    float* __restrict__ outp, int N) {
  __shared__ float hid[4][2][32];
  int tid = threadIdx.x;
  int lane = tid & 63, wslot = tid >> 6;
  int sub = lane >> 5, ol = lane & 31;
  int row = (blockIdx.x * 4 + wslot) * 2 + sub;

  float rs_i = 0.5f * (ownsum[row] + insum[row]);
  float rn_i = 1.f / (rs_i + 1e-8f);
  float di_i = rsqrtf(fmaxf(1.f + rs_i * rn_i, 1e-12f));
  float cc = 0.5f * di_i * rn_i;
  float acc = (SCALED ? di_i : di_i * di_i) * XWsrc[(size_t)row*32 + ol];
#pragma unroll
  for (int t = 0; t < K; ++t) {
    int j = eidx[row*K + t]; float v = evals[row*K + t];
    float cf;
    if constexpr (SCALED) cf = cc * v;
    else                  cf = cc * v * dinv_of(ownsum[j], insum[j]);
    acc = fmaf(cf, XWsrc[(size_t)j*32 + ol], acc);
  }
  int ne = min(indeg[row], CIN);
  for (int e = 0; e < ne; ++e) {
    int j = incol[(size_t)row*CIN + e]; float v = inval[(size_t)row*CIN + e];
    float cf;
    if constexpr (SCALED) cf = cc * v;
    else                  cf = cc * v * dinv_of(ownsum[j], insum[j]);
    acc = fmaf(cf, XWsrc[(size_t)j*32 + ol], acc);
  }
  float u0 = acc + gb[ol];
  float s = u0;
#pragma unroll
  for (int m = 1; m < 32; m <<= 1) s += __shfl_xor(s, m);
  float mean = s * (1.f/32.f);
  float d0 = u0 - mean;
  float vs = d0*d0;
#pragma unroll
  for (int m = 1; m < 32; m <<= 1) vs += __shfl_xor(vs, m);
  float rstd = rsqrtf(vs * (1.f/32.f) + 1e-5f);
  float t0 = fmaxf(d0*rstd*lg[ol] + lb[ol], 0.f);

  // MLP residual (per-wave LDS; same-wave lockstep -> no barrier)
  float hp[DIN];
#pragma unroll
  for (int d = 0; d < DIN; ++d) hp[d] = hprev[(size_t)row*DIN + d];
  float a = b0[ol];
#pragma unroll
  for (int d = 0; d < DIN; ++d) a = fmaf(hp[d], w0[d*32 + ol], a);
  hid[wslot][sub][ol] = fmaxf(a, 0.f);
  float o = b1[ol];
#pragma unroll
  for (int h = 0; h < 32; ++h) o = fmaf(hid[wslot][sub][h], w1[h*32 + ol], o);
  float hv = t0 + o;
  outp[(size_t)row*32 + ol] = hv;

  // epilogue: XWnext = dinv_row * (h @ Wnext)  (PRE-SCALED for next layer)
  hid[wslot][sub][ol] = hv;
#pragma unroll
  for (int k2 = 0; k2 < NEXTD/32; ++k2) {
    int oc = ol + 32*k2;
    float acc2 = 0.f;
#pragma unroll
    for (int d = 0; d < 32; ++d)
      acc2 = fmaf(hid[wslot][sub][d], Wnext[d*NEXTD + oc], acc2);
    XWnext[(size_t)row*NEXTD + oc] = di_i * acc2;
  }
}

// ---------------- final layer (DOUT=128): pre-scaled XW gather + LDS-staged w1 ----
__global__ __launch_bounds__(256) void k_gpost128(
    const float* __restrict__ XW,     // pre-scaled by dinv_j
    const int* __restrict__ eidx, const float* __restrict__ evals,
    const unsigned short* __restrict__ incol, const float* __restrict__ inval,
    const int* __restrict__ indeg,
    const float* __restrict__ ownsum, const float* __restrict__ insum,
    const float* __restrict__ b, const float* __restrict__ g, const float* __restrict__ bt,
    const float* __restrict__ hprev,
    const float* __restrict__ w0, const float* __restrict__ b0,
    const float* __restrict__ w1, const float* __restrict__ b1,
    float* __restrict__ out, int N) {
  __shared__ float hid_s[4][128];
  __shared__ float w1s[2048];          // 16 h-rows x 128 cols chunk (8 KB)
  int wslot = threadIdx.x >> 6;
  int row   = (blockIdx.x * blockDim.x + threadIdx.x) >> 6;
  int lane  = threadIdx.x & 63;
  int o0 = lane, o1 = lane + 64;

  float rs_i = 0.5f * (ownsum[row] + insum[row]);
  float rn_i = 1.f / (rs_i + 1e-8f);
  float di_i = rsqrtf(fmaxf(1.f + rs_i * rn_i, 1e-12f));
  float cc = 0.5f * di_i * rn_i;
  float acc0 = di_i * XW[(size_t)row*128 + o0];
  float acc1 = di_i * XW[(size_t)row*128 + o1];
#pragma unroll
  for (int t = 0; t < K; ++t) {
    int j = eidx[row*K + t];
    float cf = cc * evals[row*K + t];
    acc0 = fmaf(cf, XW[(size_t)j*128 + o0], acc0);
    acc1 = fmaf(cf, XW[(size_t)j*128 + o1], acc1);
  }
  int ne = min(indeg[row], CIN);
  for (int e = 0; e < ne; ++e) {
    int j = incol[(size_t)row*CIN + e];
    float cf = cc * inval[(size_t)row*CIN + e];
    acc0 = fmaf(cf, XW[(size_t)j*128 + o0], acc0);
    acc1 = fmaf(cf, XW[(size_t)j*128 + o1], acc1);
  }
  float u0 = acc0 + b[o0];
  float u1 = acc1 + b[o1];

  float s = u0 + u1;
#pragma unroll
  for (int m = 1; m < 64; m <<= 1) s += __shfl_xor(s, m);
  float mean = s * (1.f/128.f);
  float d0 = u0 - mean, d1 = u1 - mean;
  float vs = d0*d0 + d1*d1;
#pragma unroll
  for (int m = 1; m < 64; m <<= 1) vs += __shfl_xor(vs, m);
  float rstd = rsqrtf(vs * (1.f/128.f) + 1e-5f);
  float t0 = fmaxf(d0*rstd*g[o0] + bt[o0], 0.f);
  float t1 = fmaxf(d1*rstd*g[o1] + bt[o1], 0.f);

  float hp[32];
#pragma unroll
  for (int d = 0; d < 32; ++d) hp[d] = hprev[(size_t)row*32 + d];
  {
    float a = b0[o0];
#pragma unroll
    for (int d = 0; d < 32; ++d) a = fmaf(hp[d], w0[d*128 + o0], a);
    hid_s[wslot][o0] = fmaxf(a, 0.f);
    float a1 = b0[o1];
#pragma unroll
    for (int d = 0; d < 32; ++d) a1 = fmaf(hp[d], w0[d*128 + o1], a1);
    hid_s[wslot][o1] = fmaxf(a1, 0.f);
  }

  // out = hid @ w1 with w1 staged through LDS in 8 chunks of 16 rows.
  float r0=0.f, r1=0.f, r2=0.f, r3=0.f, q0=0.f, q1=0.f, q2=0.f, q3=0.f;
  for (int c = 0; c < 8; ++c) {
    __syncthreads();
    {
      const float4* src = (const float4*)(w1 + c*2048);
      float4* dst = (float4*)w1s;
      dst[threadIdx.x]       = src[threadIdx.x];
      dst[threadIdx.x + 256] = src[threadIdx.x + 256];
    }
    __syncthreads();
    int hb = c*16;
#pragma unroll
    for (int hh = 0; hh < 16; hh += 4) {
      float h0 = hid_s[wslot][hb+hh+0], h1 = hid_s[wslot][hb+hh+1],
            h2 = hid_s[wslot][hb+hh+2], h3 = hid_s[wslot][hb+hh+3];
      r0 = fmaf(h0, w1s[(hh+0)*128 + o0], r0); q0 = fmaf(h0, w1s[(hh+0)*128 + o1], q0);
      r1 = fmaf(h1, w1s[(hh+1)*128 + o0], r1); q1 = fmaf(h1, w1s[(hh+1)*128 + o1], q1);
      r2 = fmaf(h2, w1s[(hh+2)*128 + o0], r2); q2 = fmaf(h2, w1s[(hh+2)*128 + o1], q2);
      r3 = fmaf(h3, w1s[(hh+3)*128 + o0], r3); q3 = fmaf(h3, w1s[(hh+3)*128 + o1], q3);
    }
  }
  out[(size_t)row*128 + o0] = t0 + b1[o0] + ((r0 + r1) + (r2 + r3));
  out[(size_t)row*128 + o1] = t1 + b1[o1] + ((q0 + q1) + (q2 + q3));
}

extern "C" void kernel_launch(void* const* d_in, const int* in_sizes, int n_in,
                              void* d_out, int out_size, void* d_ws, size_t ws_size,
                              hipStream_t stream) {
  const float* x    = (const float*)d_in[0];
  const float* Wp   = (const float*)d_in[1];
  const float* bp   = (const float*)d_in[2];
  const float* gw0  = (const float*)d_in[3];
  const float* gb0  = (const float*)d_in[4];
  const float* gw1  = (const float*)d_in[5];
  const float* gb1  = (const float*)d_in[6];
  const float* gw2  = (const float*)d_in[7];
  const float* gb2  = (const float*)d_in[8];
  const float* lg0  = (const float*)d_in[9];
  const float* lb0  = (const float*)d_in[10];
  const float* lg1  = (const float*)d_in[11];
  const float* lb1  = (const float*)d_in[12];
  const float* lg2  = (const float*)d_in[13];
  const float* lb2  = (const float*)d_in[14];
  const float* riw0 = (const float*)d_in[15];
  const float* rib0 = (const float*)d_in[16];
  const float* riw1 = (const float*)d_in[17];
  const float* rib1 = (const float*)d_in[18];
  const float* rhw0 = (const float*)d_in[19];
  const float* rhb0 = (const float*)d_in[20];
  const float* rhw1 = (const float*)d_in[21];
  const float* rhb1 = (const float*)d_in[22];
  const float* row0 = (const float*)d_in[23];
  const float* rob0 = (const float*)d_in[24];
  const float* row1 = (const float*)d_in[25];
  const float* rob1 = (const float*)d_in[26];
  int N = in_sizes[0] / D_IN;   // 8192
  float* out = (float*)d_out;

  char* ws = (char*)d_ws;
  size_t off = 0;
  auto alloc = [&](size_t bytes) -> void* {
    void* p = ws + off;
    off += (bytes + 255) & ~(size_t)255;
    return p;
  };
  float* hn      = (float*)alloc((size_t)N * HP * 4);
  float* evals   = (float*)alloc((size_t)N * K * 4);
  int*   eidx    = (int*)  alloc((size_t)N * K * 4);
  float* ownsum  = (float*)alloc((size_t)N * 4);
  float* insum   = (float*)alloc((size_t)N * 4);
  int*   indeg   = (int*)  alloc((size_t)N * 4);
  float* XWa     = (float*)alloc((size_t)N * 128 * 4);
  float* XWb     = (float*)alloc((size_t)N * 32 * 4);
  float* h1      = (float*)alloc((size_t)N * 32 * 4);
  float* h2      = (float*)alloc((size_t)N * 32 * 4);
  short* hnb     = (short*)alloc((size_t)N * 32 * 2);
  unsigned short* incol = (unsigned short*)alloc((size_t)N * CIN * 2);
  float* inval   = (float*)alloc((size_t)N * CIN * 4);
  (void)ws_size; (void)n_in; (void)out_size;

  const int B = 256;
  hipLaunchKernelGGL(k_proj, dim3((N + B - 1) / B), dim3(B), 0, stream,
                     x, Wp, bp, gw0, hn, hnb, XWa, insum, indeg, N);
  // fused thresh + MFMA scan + exact top-6: 512 blocks x 512 threads
  hipLaunchKernelGGL(k_scanfin, dim3(N / 16), dim3(512), 0, stream,
                     hn, hnb, evals, eidx, ownsum, insum, indeg, incol, inval, N);

  // layer 0: XWa unscaled -> h1; epilogue XWb = dinv * (h1 @ gw1)
  hipLaunchKernelGGL((k_gpost32<20, 32, false>), dim3(N / 8), dim3(B), 0, stream,
                     XWa, eidx, evals, incol, inval, indeg, ownsum, insum,
                     gb0, lg0, lb0, x, riw0, rib0, riw1, rib1, gw1, XWb, h1, N);
  // layer 1: XWb pre-scaled -> h2; epilogue XWa = dinv * (h2 @ gw2)
  hipLaunchKernelGGL((k_gpost32<32, 128, true>), dim3(N / 8), dim3(B), 0, stream,
                     XWb, eidx, evals, incol, inval, indeg, ownsum, insum,
                     gb1, lg1, lb1, h1, rhw0, rhb0, rhw1, rhb1, gw2, XWa, h2, N);
  // layer 2: XWa pre-scaled -> out
  hipLaunchKernelGGL(k_gpost128, dim3(N / 4), dim3(B), 0, stream,
                     XWa, eidx, evals, incol, inval, indeg, ownsum, insum,
                     gb2, lg2, lb2, h2, row0, rob0, row1, rob1, out, N);
}

// Round 25
// 165.648 us; speedup vs baseline: 1.0288x; 1.0288x over previous
//
#include <hip/hip_runtime.h>

constexpr int D_IN = 20;   // input feature dim
constexpr int HP   = 16;   // projection dim
constexpr int K    = 6;    // neighbors
constexpr int SAMP = 512;  // threshold sample size
constexpr int CAPL = 384;  // per-row LDS hit-buffer capacity (mean ~115)
constexpr int CIN  = 128;  // per-row in-edge slots
constexpr float MARGIN = 0.02f;  // covers bf16-vs-fp32 dot error

typedef __attribute__((ext_vector_type(8))) short bf16x8;
typedef __attribute__((ext_vector_type(4))) float f32x4;

// Sequential fmaf dot — MUST be bit-identical in phase 3 (exact selection).
__device__ __forceinline__ float dot16_seq(const float4* q, const float4* c) {
  float s = 0.f;
#pragma unroll
  for (int m = 0; m < 4; ++m) {
    s = fmaf(q[m].x, c[m].x, s);
    s = fmaf(q[m].y, c[m].y, s);
    s = fmaf(q[m].z, c[m].z, s);
    s = fmaf(q[m].w, c[m].w, s);
  }
  return s;
}

// round-to-nearest-even f32 -> bf16 bits
__device__ __forceinline__ short f2bf(float f) {
  unsigned u = __float_as_uint(f);
  unsigned r = (u + 0x7fffu + ((u >> 16) & 1u)) >> 16;
  return (short)r;
}

__device__ __forceinline__ float dinv_of(float own, float ins) {
  float rs = 0.5f * (own + ins);
  float rn = 1.f / (rs + 1e-8f);
  return rsqrtf(fmaxf(1.f + rs * rn, 1e-12f));
}

// ---- projection + row-normalize + bf16 copy + XW0 + counter zeroing ----
__global__ void k_proj(const float* __restrict__ x, const float* __restrict__ Wp,
                       const float* __restrict__ bp, const float* __restrict__ gw0,
                       float* __restrict__ hn, short* __restrict__ hnb,
                       float* __restrict__ XW0,
                       float* __restrict__ insum, int* __restrict__ indeg, int N) {
  int i = blockIdx.x * blockDim.x + threadIdx.x;
  if (i >= N) return;
  insum[i] = 0.f; indeg[i] = 0;
  float xr[D_IN];
#pragma unroll
  for (int d = 0; d < D_IN; ++d) xr[d] = x[i*D_IN + d];
  float hv[HP];
  float nrm2 = 0.f;
#pragma unroll
  for (int h = 0; h < HP; ++h) {
    float a = bp[h];
#pragma unroll
    for (int d = 0; d < D_IN; ++d) a += xr[d] * Wp[d*HP + h];
    hv[h] = a;
    nrm2 += a * a;
  }
  float inv = 1.f / fmaxf(sqrtf(nrm2), 1e-12f);
#pragma unroll
  for (int h = 0; h < HP; ++h) {
    float v = hv[h] * inv;
    hn[i*HP + h] = v;
    hnb[(size_t)i*32 + h] = f2bf(v);
  }
#pragma unroll
  for (int h = 0; h < HP; ++h) hnb[(size_t)i*32 + 16 + h] = 0;
#pragma unroll
  for (int oc = 0; oc < 32; ++oc) {
    float a = 0.f;
#pragma unroll
    for (int d = 0; d < D_IN; ++d) a += xr[d] * gw0[d*32 + oc];
    XW0[(size_t)i*32 + oc] = a;
  }
}

// ---------------- per-lane top-6 in NAMED registers (phase 3 only) ----
struct Top6 { float v0,v1,v2,v3,v4,v5; int i0,i1,i2,i3,i4,i5; };

__device__ __forceinline__ void t6_init(Top6& t) {
  t.v0=t.v1=t.v2=t.v3=t.v4=t.v5=-1e30f;
  t.i0=t.i1=t.i2=t.i3=t.i4=t.i5=-1;
}

#define T6_SWAP(a,b,ia,ib) { float tv=a; a=b; b=tv; int ti=ia; ia=ib; ib=ti; }

__device__ __forceinline__ void t6_insert(Top6& t, float s, int c) {
  if (s > t.v5) {
    t.v5 = s; t.i5 = c;
    if (t.v5 > t.v4) { T6_SWAP(t.v4, t.v5, t.i4, t.i5); }
    if (t.v4 > t.v3) { T6_SWAP(t.v3, t.v4, t.i3, t.i4); }
    if (t.v3 > t.v2) { T6_SWAP(t.v2, t.v3, t.i2, t.i3); }
    if (t.v2 > t.v1) { T6_SWAP(t.v1, t.v2, t.i1, t.i2); }
    if (t.v1 > t.v0) { T6_SWAP(t.v0, t.v1, t.i0, t.i1); }
  }
}

__device__ __forceinline__ void t6_best(const Top6& t, float& cv, int& ci) {
  cv = t.v0; ci = t.i0;
  if (t.v1 > cv || (t.v1 == cv && (unsigned)t.i1 < (unsigned)ci)) { cv = t.v1; ci = t.i1; }
  if (t.v2 > cv || (t.v2 == cv && (unsigned)t.i2 < (unsigned)ci)) { cv = t.v2; ci = t.i2; }
  if (t.v3 > cv || (t.v3 == cv && (unsigned)t.i3 < (unsigned)ci)) { cv = t.v3; ci = t.i3; }
  if (t.v4 > cv || (t.v4 == cv && (unsigned)t.i4 < (unsigned)ci)) { cv = t.v4; ci = t.i4; }
  if (t.v5 > cv || (t.v5 == cv && (unsigned)t.i5 < (unsigned)ci)) { cv = t.v5; ci = t.i5; }
}

__device__ __forceinline__ void t6_consume(Top6& t, int mi) {
  if (t.i0 == mi) t.v0 = -1e30f;
  if (t.i1 == mi) t.v1 = -1e30f;
  if (t.i2 == mi) t.v2 = -1e30f;
  if (t.i3 == mi) t.v3 = -1e30f;
  if (t.i4 == mi) t.v4 = -1e30f;
  if (t.i5 == mi) t.v5 = -1e30f;
}

// ---- FUSED: lane-max threshold + MFMA scan (LDS hit buffers) + exact top-6 ----
// 512 blocks x 1024 threads (R22's winning shape). Phase 1 avoids the Top6
// insert chain entirely (the VGPR=32 remat hog): per-lane running max over 8
// sample candidates, then tau = 6 rounds of wave-max-and-consume over the 64
// lane-maxes. tau = 6th-largest of a 64-subset of the sample <= true sample
// 6th-largest <= row's true 6th-largest -> valid lower bound; ties only
// lower tau (still valid). Phase 3 rescores exact fp32 -> same selection.
__global__ __launch_bounds__(1024) void k_scanfin(
    const float* __restrict__ hn, const short* __restrict__ hnb,
    float* __restrict__ evals, int* __restrict__ eidx,
    float* __restrict__ ownsum, float* insum, int* indeg,
    unsigned short* __restrict__ incol, float* __restrict__ inval, int N) {
  __shared__ unsigned short hbuf[16][CAPL];   // 12 KB
  __shared__ int cntl[16];
  __shared__ float tau_s[16];
  int tid = threadIdx.x;
  int wave = tid >> 6, lane = tid & 63;
  int r0 = blockIdx.x * 16;
  const float4* hn4 = (const float4*)hn;

  if (tid < 16) cntl[tid] = 0;

  // ---- phase 1: lane-max threshold, wave per row ----
  {
    int row = r0 + wave;
    float4 q[4];
#pragma unroll
    for (int m = 0; m < 4; ++m) q[m] = hn4[(size_t)row*4 + m];
    float mx = -1e30f;
#pragma unroll
    for (int k = 0; k < SAMP/64; ++k) {
      int c = lane + 64*k;
      float4 cv[4];
#pragma unroll
      for (int m = 0; m < 4; ++m) cv[m] = hn4[(size_t)c*4 + m];
      float s = dot16_seq(q, cv);
      if (c != row) mx = fmaxf(mx, s);
    }
    float last = -1e30f;
    for (int sel = 0; sel < K; ++sel) {
      float mv = mx;
#pragma unroll
      for (int m = 1; m < 64; m <<= 1) mv = fmaxf(mv, __shfl_xor(mv, m));
      if (mx == mv) mx = -1e30f;     // owner(s) consume; ties lower tau (ok)
      last = mv;
    }
    if (lane == 0) tau_s[wave] = last;
  }
  __syncthreads();

  // ---- phase 2: MFMA scan into LDS hit buffers ----
  {
    int half = lane >> 4;            // 0..3
    int l16  = lane & 15;
    bf16x8 a = *(const bf16x8*)(hnb + (size_t)(r0 + l16)*32 + half*8);
    float tm0 = tau_s[half*4+0] - MARGIN, tm1 = tau_s[half*4+1] - MARGIN,
          tm2 = tau_s[half*4+2] - MARGIN, tm3 = tau_s[half*4+3] - MARGIN;
    f32x4 zero = {0.f, 0.f, 0.f, 0.f};
    const int SPANW = N / 16;        // 512 cands per wave
    int jb0 = wave * SPANW;

#define APPB(R, COND)                                                        \
    {                                                                        \
      unsigned long long mr = __ballot(COND);                                \
      if (l16 == 0) {                                                        \
        unsigned mask = (unsigned)(mr >> (16*half)) & 0xFFFFu;               \
        if (mask) {                                                          \
          int rl = 4*half + (R);                                             \
          int pos = atomicAdd(&cntl[rl], __popc(mask));                      \
          unsigned mm = mask;                                                \
          while (mm) {                                                       \
            int bx = __ffs(mm) - 1; mm &= mm - 1;                            \
            if (pos < CAPL) hbuf[rl][pos] = (unsigned short)(jb + bx);       \
            ++pos;                                                           \
          }                                                                  \
        }                                                                    \
      }                                                                      \
    }

#pragma unroll 4
    for (int jt = 0; jt < SPANW; jt += 16) {
      int jb = jb0 + jt;
      bf16x8 b = *(const bf16x8*)(hnb + (size_t)(jb + l16)*32 + half*8);
      f32x4 d = __builtin_amdgcn_mfma_f32_16x16x32_bf16(a, b, zero, 0, 0, 0);
      bool h0 = d[0] >= tm0, h1 = d[1] >= tm1, h2 = d[2] >= tm2, h3 = d[3] >= tm3;
      if (__any(h0 | h1 | h2 | h3)) {
        APPB(0, h0) APPB(1, h1) APPB(2, h2) APPB(3, h3)
      }
    }
#undef APPB
  }
  __syncthreads();

  // ---- phase 3: exact fp32 top-6 from LDS hit list, wave per row ----
  {
    int row = r0 + wave;
    int n = min(cntl[wave], CAPL);
    float4 q[4];
#pragma unroll
    for (int m = 0; m < 4; ++m) q[m] = hn4[(size_t)row*4 + m];
    Top6 t; t6_init(t);
    for (int e = lane; e < n; e += 64) {
      int j = hbuf[wave][e];
      if (j != row) {
        float4 cv[4];
#pragma unroll
        for (int m = 0; m < 4; ++m) cv[m] = hn4[(size_t)j*4 + m];
        float sc = dot16_seq(q, cv);
        t6_insert(t, sc, j);
      }
    }
    float osum = 0.f;
    for (int sel = 0; sel < K; ++sel) {
      float cv; int ci;
      t6_best(t, cv, ci);
      float mv = cv; int mi = ci;
#pragma unroll
      for (int m = 1; m < 64; m <<= 1) {
        float ov = __shfl_xor(mv, m);
        int   oi = __shfl_xor(mi, m);
        if (ov > mv || (ov == mv && (unsigned)oi < (unsigned)mi)) { mv = ov; mi = oi; }
      }
      t6_consume(t, mi);
      if (lane == 0) {
        evals[row*K + sel] = mv;
        eidx [row*K + sel] = mi;
        osum += mv;
        atomicAdd(&insum[mi], mv);
        int pos = atomicAdd(&indeg[mi], 1);
        if (pos < CIN) {
          incol[(size_t)mi*CIN + pos] = (unsigned short)row;
          inval[(size_t)mi*CIN + pos] = mv;
        }
      }
    }
    if (lane == 0) ownsum[row] = osum;
  }
}

// ---- DOUT=32 layer: GCN + LN + ReLU + MLP residual, 2 rows/wave.
// SCALED: XWsrc already carries dinv_j -> per-edge coef is cc*v.
// Epilogue writes XWnext PRE-SCALED by dinv_row.
template<int DIN, int NEXTD, bool SCALED>
__global__ __launch_bounds__(256) void k_gpost32(
    const float* __restrict__ XWsrc,
    const int* __restrict__ eidx, const float* __restrict__ evals,
    const unsigned short* __restrict__ incol, const float* __restrict__ inval,
    const int* __restrict__ indeg,
    const float* __restrict__ ownsum, const float* __restrict__ insum,
    const float* __restrict__ gb, const float* __restrict__ lg, const float* __restrict__ lb,
    const float* __restrict__ hprev,
    const float* __restrict__ w0, const float* __restrict__ b0,
    const float* __restrict__ w1, const float* __restrict__ b1,
    const float* __restrict__ Wnext, float* __restrict__ XWnext,
    float* __restrict__ outp, int N) {
  __shared__ float hid[4][2][32];
  int tid = threadIdx.x;
  int lane = tid & 63, wslot = tid >> 6;
  int sub = lane >> 5, ol = lane & 31;
  int row = (blockIdx.x * 4 + wslot) * 2 + sub;

  float rs_i = 0.5f * (ownsum[row] + insum[row]);
  float rn_i = 1.f / (rs_i + 1e-8f);
  float di_i = rsqrtf(fmaxf(1.f + rs_i * rn_i, 1e-12f));
  float cc = 0.5f * di_i * rn_i;
  float acc = (SCALED ? di_i : di_i * di_i) * XWsrc[(size_t)row*32 + ol];
#pragma unroll
  for (int t = 0; t < K; ++t) {
    int j = eidx[row*K + t]; float v = evals[row*K + t];
    float cf;
    if constexpr (SCALED) cf = cc * v;
    else                  cf = cc * v * dinv_of(ownsum[j], insum[j]);
    acc = fmaf(cf, XWsrc[(size_t)j*32 + ol], acc);
  }
  int ne = min(indeg[row], CIN);
  for (int e = 0; e < ne; ++e) {
    int j = incol[(size_t)row*CIN + e]; float v = inval[(size_t)row*CIN + e];
    float cf;
    if constexpr (SCALED) cf = cc * v;
    else                  cf = cc * v * dinv_of(ownsum[j], insum[j]);
    acc = fmaf(cf, XWsrc[(size_t)j*32 + ol], acc);
  }
  float u0 = acc + gb[ol];
  float s = u0;
#pragma unroll
  for (int m = 1; m < 32; m <<= 1) s += __shfl_xor(s, m);
  float mean = s * (1.f/32.f);
  float d0 = u0 - mean;
  float vs = d0*d0;
#pragma unroll
  for (int m = 1; m < 32; m <<= 1) vs += __shfl_xor(vs, m);
  float rstd = rsqrtf(vs * (1.f/32.f) + 1e-5f);
  float t0 = fmaxf(d0*rstd*lg[ol] + lb[ol], 0.f);

  // MLP residual (per-wave LDS; same-wave lockstep -> no barrier)
  float hp[DIN];
#pragma unroll
  for (int d = 0; d < DIN; ++d) hp[d] = hprev[(size_t)row*DIN + d];
  float a = b0[ol];
#pragma unroll
  for (int d = 0; d < DIN; ++d) a = fmaf(hp[d], w0[d*32 + ol], a);
  hid[wslot][sub][ol] = fmaxf(a, 0.f);
  float o = b1[ol];
#pragma unroll
  for (int h = 0; h < 32; ++h) o = fmaf(hid[wslot][sub][h], w1[h*32 + ol], o);
  float hv = t0 + o;
  outp[(size_t)row*32 + ol] = hv;

  // epilogue: XWnext = dinv_row * (h @ Wnext)  (PRE-SCALED for next layer)
  hid[wslot][sub][ol] = hv;
#pragma unroll
  for (int k2 = 0; k2 < NEXTD/32; ++k2) {
    int oc = ol + 32*k2;
    float acc2 = 0.f;
#pragma unroll
    for (int d = 0; d < 32; ++d)
      acc2 = fmaf(hid[wslot][sub][d], Wnext[d*NEXTD + oc], acc2);
    XWnext[(size_t)row*NEXTD + oc] = di_i * acc2;
  }
}

// ---------------- final layer (DOUT=128): pre-scaled XW gather + LDS-staged w1 ----
__global__ __launch_bounds__(256) void k_gpost128(
    const float* __restrict__ XW,     // pre-scaled by dinv_j
    const int* __restrict__ eidx, const float* __restrict__ evals,
    const unsigned short* __restrict__ incol, const float* __restrict__ inval,
    const int* __restrict__ indeg,
    const float* __restrict__ ownsum, const float* __restrict__ insum,
    const float* __restrict__ b, const float* __restrict__ g, const float* __restrict__ bt,
    const float* __restrict__ hprev,
    const float* __restrict__ w0, const float* __restrict__ b0,
    const float* __restrict__ w1, const float* __restrict__ b1,
    float* __restrict__ out, int N) {
  __shared__ float hid_s[4][128];
  __shared__ float w1s[2048];          // 16 h-rows x 128 cols chunk (8 KB)
  int wslot = threadIdx.x >> 6;
  int row   = (blockIdx.x * blockDim.x + threadIdx.x) >> 6;
  int lane  = threadIdx.x & 63;
  int o0 = lane, o1 = lane + 64;

  float rs_i = 0.5f * (ownsum[row] + insum[row]);
  float rn_i = 1.f / (rs_i + 1e-8f);
  float di_i = rsqrtf(fmaxf(1.f + rs_i * rn_i, 1e-12f));
  float cc = 0.5f * di_i * rn_i;
  float acc0 = di_i * XW[(size_t)row*128 + o0];
  float acc1 = di_i * XW[(size_t)row*128 + o1];
#pragma unroll
  for (int t = 0; t < K; ++t) {
    int j = eidx[row*K + t];
    float cf = cc * evals[row*K + t];
    acc0 = fmaf(cf, XW[(size_t)j*128 + o0], acc0);
    acc1 = fmaf(cf, XW[(size_t)j*128 + o1], acc1);
  }
  int ne = min(indeg[row], CIN);
  for (int e = 0; e < ne; ++e) {
    int j = incol[(size_t)row*CIN + e];
    float cf = cc * inval[(size_t)row*CIN + e];
    acc0 = fmaf(cf, XW[(size_t)j*128 + o0], acc0);
    acc1 = fmaf(cf, XW[(size_t)j*128 + o1], acc1);
  }
  float u0 = acc0 + b[o0];
  float u1 = acc1 + b[o1];

  float s = u0 + u1;
#pragma unroll
  for (int m = 1; m < 64; m <<= 1) s += __shfl_xor(s, m);
  float mean = s * (1.f/128.f);
  float d0 = u0 - mean, d1 = u1 - mean;
  float vs = d0*d0 + d1*d1;
#pragma unroll
  for (int m = 1; m < 64; m <<= 1) vs += __shfl_xor(vs, m);
  float rstd = rsqrtf(vs * (1.f/128.f) + 1e-5f);
  float t0 = fmaxf(d0*rstd*g[o0] + bt[o0], 0.f);
  float t1 = fmaxf(d1*rstd*g[o1] + bt[o1], 0.f);

  float hp[32];
#pragma unroll
  for (int d = 0; d < 32; ++d) hp[d] = hprev[(size_t)row*32 + d];
  {
    float a = b0[o0];
#pragma unroll
    for (int d = 0; d < 32; ++d) a = fmaf(hp[d], w0[d*128 + o0], a);
    hid_s[wslot][o0] = fmaxf(a, 0.f);
    float a1 = b0[o1];
#pragma unroll
    for (int d = 0; d < 32; ++d) a1 = fmaf(hp[d], w0[d*128 + o1], a1);
    hid_s[wslot][o1] = fmaxf(a1, 0.f);
  }

  // out = hid @ w1 with w1 staged through LDS in 8 chunks of 16 rows.
  float r0=0.f, r1=0.f, r2=0.f, r3=0.f, q0=0.f, q1=0.f, q2=0.f, q3=0.f;
  for (int c = 0; c < 8; ++c) {
    __syncthreads();
    {
      const float4* src = (const float4*)(w1 + c*2048);
      float4* dst = (float4*)w1s;
      dst[threadIdx.x]       = src[threadIdx.x];
      dst[threadIdx.x + 256] = src[threadIdx.x + 256];
    }
    __syncthreads();
    int hb = c*16;
#pragma unroll
    for (int hh = 0; hh < 16; hh += 4) {
      float h0 = hid_s[wslot][hb+hh+0], h1 = hid_s[wslot][hb+hh+1],
            h2 = hid_s[wslot][hb+hh+2], h3 = hid_s[wslot][hb+hh+3];
      r0 = fmaf(h0, w1s[(hh+0)*128 + o0], r0); q0 = fmaf(h0, w1s[(hh+0)*128 + o1], q0);
      r1 = fmaf(h1, w1s[(hh+1)*128 + o0], r1); q1 = fmaf(h1, w1s[(hh+1)*128 + o1], q1);
      r2 = fmaf(h2, w1s[(hh+2)*128 + o0], r2); q2 = fmaf(h2, w1s[(hh+2)*128 + o1], q2);
      r3 = fmaf(h3, w1s[(hh+3)*128 + o0], r3); q3 = fmaf(h3, w1s[(hh+3)*128 + o1], q3);
    }
  }
  out[(size_t)row*128 + o0] = t0 + b1[o0] + ((r0 + r1) + (r2 + r3));
  out[(size_t)row*128 + o1] = t1 + b1[o1] + ((q0 + q1) + (q2 + q3));
}

extern "C" void kernel_launch(void* const* d_in, const int* in_sizes, int n_in,
                              void* d_out, int out_size, void* d_ws, size_t ws_size,
                              hipStream_t stream) {
  const float* x    = (const float*)d_in[0];
  const float* Wp   = (const float*)d_in[1];
  const float* bp   = (const float*)d_in[2];
  const float* gw0  = (const float*)d_in[3];
  const float* gb0  = (const float*)d_in[4];
  const float* gw1  = (const float*)d_in[5];
  const float* gb1  = (const float*)d_in[6];
  const float* gw2  = (const float*)d_in[7];
  const float* gb2  = (const float*)d_in[8];
  const float* lg0  = (const float*)d_in[9];
  const float* lb0  = (const float*)d_in[10];
  const float* lg1  = (const float*)d_in[11];
  const float* lb1  = (const float*)d_in[12];
  const float* lg2  = (const float*)d_in[13];
  const float* lb2  = (const float*)d_in[14];
  const float* riw0 = (const float*)d_in[15];
  const float* rib0 = (const float*)d_in[16];
  const float* riw1 = (const float*)d_in[17];
  const float* rib1 = (const float*)d_in[18];
  const float* rhw0 = (const float*)d_in[19];
  const float* rhb0 = (const float*)d_in[20];
  const float* rhw1 = (const float*)d_in[21];
  const float* rhb1 = (const float*)d_in[22];
  const float* row0 = (const float*)d_in[23];
  const float* rob0 = (const float*)d_in[24];
  const float* row1 = (const float*)d_in[25];
  const float* rob1 = (const float*)d_in[26];
  int N = in_sizes[0] / D_IN;   // 8192
  float* out = (float*)d_out;

  char* ws = (char*)d_ws;
  size_t off = 0;
  auto alloc = [&](size_t bytes) -> void* {
    void* p = ws + off;
    off += (bytes + 255) & ~(size_t)255;
    return p;
  };
  float* hn      = (float*)alloc((size_t)N * HP * 4);
  float* evals   = (float*)alloc((size_t)N * K * 4);
  int*   eidx    = (int*)  alloc((size_t)N * K * 4);
  float* ownsum  = (float*)alloc((size_t)N * 4);
  float* insum   = (float*)alloc((size_t)N * 4);
  int*   indeg   = (int*)  alloc((size_t)N * 4);
  float* XWa     = (float*)alloc((size_t)N * 128 * 4);
  float* XWb     = (float*)alloc((size_t)N * 32 * 4);
  float* h1      = (float*)alloc((size_t)N * 32 * 4);
  float* h2      = (float*)alloc((size_t)N * 32 * 4);
  short* hnb     = (short*)alloc((size_t)N * 32 * 2);
  unsigned short* incol = (unsigned short*)alloc((size_t)N * CIN * 2);
  float* inval   = (float*)alloc((size_t)N * CIN * 4);
  (void)ws_size; (void)n_in; (void)out_size;

  const int B = 256;
  hipLaunchKernelGGL(k_proj, dim3((N + B - 1) / B), dim3(B), 0, stream,
                     x, Wp, bp, gw0, hn, hnb, XWa, insum, indeg, N);
  // fused lane-max thresh + MFMA scan + exact top-6: 512 blocks x 1024 threads
  hipLaunchKernelGGL(k_scanfin, dim3(N / 16), dim3(1024), 0, stream,
                     hn, hnb, evals, eidx, ownsum, insum, indeg, incol, inval, N);

  // layer 0: XWa unscaled -> h1; epilogue XWb = dinv * (h1 @ gw1)
  hipLaunchKernelGGL((k_gpost32<20, 32, false>), dim3(N / 8), dim3(B), 0, stream,
                     XWa, eidx, evals, incol, inval, indeg, ownsum, insum,
                     gb0, lg0, lb0, x, riw0, rib0, riw1, rib1, gw1, XWb, h1, N);
  // layer 1: XWb pre-scaled -> h2; epilogue XWa = dinv * (h2 @ gw2)
  hipLaunchKernelGGL((k_gpost32<32, 128, true>), dim3(N / 8), dim3(B), 0, stream,
                     XWb, eidx, evals, incol, inval, indeg, ownsum, insum,
                     gb1, lg1, lb1, h1, rhw0, rhb0, rhw1, rhb1, gw2, XWa, h2, N);
  // layer 2: XWa pre-scaled -> out
  hipLaunchKernelGGL(k_gpost128, dim3(N / 4), dim3(B), 0, stream,
                     XWa, eidx, evals, incol, inval, indeg, ownsum, insum,
                     gb2, lg2, lb2, h2, row0, rob0, row1, rob1, out, N);
}

// Round 27
// 147.358 us; speedup vs baseline: 1.1565x; 1.1241x over previous
//
#include <hip/hip_runtime.h>

constexpr int D_IN = 20;   // input feature dim
constexpr int HP   = 16;   // projection dim
constexpr int K    = 6;    // neighbors
constexpr int SAMP = 512;  // threshold sample size (256 overflowed CAPL: sigma~78)
constexpr int CAPL = 384;  // per-row LDS hit-buffer capacity (mean ~96, +7.4 sigma)
constexpr int CIN  = 128;  // per-row in-edge slots
constexpr float MARGIN = 0.02f;  // covers bf16-vs-fp32 dot error

typedef __attribute__((ext_vector_type(8))) short bf16x8;
typedef __attribute__((ext_vector_type(4))) float f32x4;

// Sequential fmaf dot — MUST be bit-identical across thresh/final.
__device__ __forceinline__ float dot16_seq(const float4* q, const float4* c) {
  float s = 0.f;
#pragma unroll
  for (int m = 0; m < 4; ++m) {
    s = fmaf(q[m].x, c[m].x, s);
    s = fmaf(q[m].y, c[m].y, s);
    s = fmaf(q[m].z, c[m].z, s);
    s = fmaf(q[m].w, c[m].w, s);
  }
  return s;
}

// round-to-nearest-even f32 -> bf16 bits
__device__ __forceinline__ short f2bf(float f) {
  unsigned u = __float_as_uint(f);
  unsigned r = (u + 0x7fffu + ((u >> 16) & 1u)) >> 16;
  return (short)r;
}

__device__ __forceinline__ float dinv_of(float own, float ins) {
  float rs = 0.5f * (own + ins);
  float rn = 1.f / (rs + 1e-8f);
  return rsqrtf(fmaxf(1.f + rs * rn, 1e-12f));
}

// ---- projection + row-normalize + bf16 copy + XW0 + counter zeroing ----
__global__ void k_proj(const float* __restrict__ x, const float* __restrict__ Wp,
                       const float* __restrict__ bp, const float* __restrict__ gw0,
                       float* __restrict__ hn, short* __restrict__ hnb,
                       float* __restrict__ XW0,
                       float* __restrict__ insum, int* __restrict__ indeg, int N) {
  int i = blockIdx.x * blockDim.x + threadIdx.x;
  if (i >= N) return;
  insum[i] = 0.f; indeg[i] = 0;
  float xr[D_IN];
#pragma unroll
  for (int d = 0; d < D_IN; ++d) xr[d] = x[i*D_IN + d];
  float hv[HP];
  float nrm2 = 0.f;
#pragma unroll
  for (int h = 0; h < HP; ++h) {
    float a = bp[h];
#pragma unroll
    for (int d = 0; d < D_IN; ++d) a += xr[d] * Wp[d*HP + h];
    hv[h] = a;
    nrm2 += a * a;
  }
  float inv = 1.f / fmaxf(sqrtf(nrm2), 1e-12f);
#pragma unroll
  for (int h = 0; h < HP; ++h) {
    float v = hv[h] * inv;
    hn[i*HP + h] = v;
    hnb[(size_t)i*32 + h] = f2bf(v);
  }
#pragma unroll
  for (int h = 0; h < HP; ++h) hnb[(size_t)i*32 + 16 + h] = 0;
#pragma unroll
  for (int oc = 0; oc < 32; ++oc) {
    float a = 0.f;
#pragma unroll
    for (int d = 0; d < D_IN; ++d) a += xr[d] * gw0[d*32 + oc];
    XW0[(size_t)i*32 + oc] = a;
  }
}

// ---------------- per-lane top-6 in NAMED registers ----
struct Top6 { float v0,v1,v2,v3,v4,v5; int i0,i1,i2,i3,i4,i5; };

__device__ __forceinline__ void t6_init(Top6& t) {
  t.v0=t.v1=t.v2=t.v3=t.v4=t.v5=-1e30f;
  t.i0=t.i1=t.i2=t.i3=t.i4=t.i5=-1;
}

#define T6_SWAP(a,b,ia,ib) { float tv=a; a=b; b=tv; int ti=ia; ia=ib; ib=ti; }

__device__ __forceinline__ void t6_insert(Top6& t, float s, int c) {
  if (s > t.v5) {
    t.v5 = s; t.i5 = c;
    if (t.v5 > t.v4) { T6_SWAP(t.v4, t.v5, t.i4, t.i5); }
    if (t.v4 > t.v3) { T6_SWAP(t.v3, t.v4, t.i3, t.i4); }
    if (t.v3 > t.v2) { T6_SWAP(t.v2, t.v3, t.i2, t.i3); }
    if (t.v2 > t.v1) { T6_SWAP(t.v1, t.v2, t.i1, t.i2); }
    if (t.v1 > t.v0) { T6_SWAP(t.v0, t.v1, t.i0, t.i1); }
  }
}

__device__ __forceinline__ void t6_best(const Top6& t, float& cv, int& ci) {
  cv = t.v0; ci = t.i0;
  if (t.v1 > cv || (t.v1 == cv && (unsigned)t.i1 < (unsigned)ci)) { cv = t.v1; ci = t.i1; }
  if (t.v2 > cv || (t.v2 == cv && (unsigned)t.i2 < (unsigned)ci)) { cv = t.v2; ci = t.i2; }
  if (t.v3 > cv || (t.v3 == cv && (unsigned)t.i3 < (unsigned)ci)) { cv = t.v3; ci = t.i3; }
  if (t.v4 > cv || (t.v4 == cv && (unsigned)t.i4 < (unsigned)ci)) { cv = t.v4; ci = t.i4; }
  if (t.v5 > cv || (t.v5 == cv && (unsigned)t.i5 < (unsigned)ci)) { cv = t.v5; ci = t.i5; }
}

__device__ __forceinline__ void t6_consume(Top6& t, int mi) {
  if (t.i0 == mi) t.v0 = -1e30f;
  if (t.i1 == mi) t.v1 = -1e30f;
  if (t.i2 == mi) t.v2 = -1e30f;
  if (t.i3 == mi) t.v3 = -1e30f;
  if (t.i4 == mi) t.v4 = -1e30f;
  if (t.i5 == mi) t.v5 = -1e30f;
}

// ---------------- threshold pass: exact 6th-largest over SAMP-sample, wave per row
// (separate 256-thread kernel: sane VGPR codegen, R21's proven shape)
__global__ __launch_bounds__(256) void k_thresh(const float* __restrict__ hn,
                                                float* __restrict__ tau, int N) {
  int wave = threadIdx.x >> 6, lane = threadIdx.x & 63;
  int row = blockIdx.x * 4 + wave;
  const float4* hn4 = (const float4*)hn;
  float4 q[4];
#pragma unroll
  for (int m = 0; m < 4; ++m) q[m] = hn4[(size_t)row*4 + m];
  Top6 t; t6_init(t);
#pragma unroll
  for (int k = 0; k < SAMP/64; ++k) {
    int c = lane + 64*k;
    if (c != row) {
      float4 cv[4];
#pragma unroll
      for (int m = 0; m < 4; ++m) cv[m] = hn4[(size_t)c*4 + m];
      float s = dot16_seq(q, cv);
      t6_insert(t, s, c);
    }
  }
  float last = -1e30f;
  for (int sel = 0; sel < K; ++sel) {
    float cv; int ci;
    t6_best(t, cv, ci);
    float mv = cv; int mi = ci;
#pragma unroll
    for (int m = 1; m < 64; m <<= 1) {
      float ov = __shfl_xor(mv, m);
      int   oi = __shfl_xor(mi, m);
      if (ov > mv || (ov == mv && (unsigned)oi < (unsigned)mi)) { mv = ov; mi = oi; }
    }
    t6_consume(t, mi);
    last = mv;
  }
  if (lane == 0) tau[row] = last;
}

// ---- FUSED phases 2+3: MFMA scan (LDS hit buffers) + exact top-6 ----
// 512 blocks x 1024 threads; tau read from global (wave-uniform s_load).
__global__ __launch_bounds__(1024) void k_scan23(
    const float* __restrict__ hn, const short* __restrict__ hnb,
    const float* __restrict__ tau,
    float* __restrict__ evals, int* __restrict__ eidx,
    float* __restrict__ ownsum, float* insum, int* indeg,
    unsigned short* __restrict__ incol, float* __restrict__ inval, int N) {
  __shared__ unsigned short hbuf[16][CAPL];   // 12 KB
  __shared__ int cntl[16];
  int tid = threadIdx.x;
  int wave = tid >> 6, lane = tid & 63;
  int r0 = blockIdx.x * 16;
  const float4* hn4 = (const float4*)hn;

  if (tid < 16) cntl[tid] = 0;
  __syncthreads();

  // ---- phase 2: MFMA scan into LDS hit buffers ----
  {
    int half = lane >> 4;            // 0..3
    int l16  = lane & 15;
    bf16x8 a = *(const bf16x8*)(hnb + (size_t)(r0 + l16)*32 + half*8);
    float4 t4 = *(const float4*)(tau + r0 + half*4);
    float tm0 = t4.x - MARGIN, tm1 = t4.y - MARGIN,
          tm2 = t4.z - MARGIN, tm3 = t4.w - MARGIN;
    f32x4 zero = {0.f, 0.f, 0.f, 0.f};
    const int SPANW = N / 16;        // 512 cands per wave
    int jb0 = wave * SPANW;

#define APPB(R, COND)                                                        \
    {                                                                        \
      unsigned long long mr = __ballot(COND);                                \
      if (l16 == 0) {                                                        \
        unsigned mask = (unsigned)(mr >> (16*half)) & 0xFFFFu;               \
        if (mask) {                                                          \
          int rl = 4*half + (R);                                             \
          int pos = atomicAdd(&cntl[rl], __popc(mask));                      \
          unsigned mm = mask;                                                \
          while (mm) {                                                       \
            int bx = __ffs(mm) - 1; mm &= mm - 1;                            \
            if (pos < CAPL) hbuf[rl][pos] = (unsigned short)(jb + bx);       \
            ++pos;                                                           \
          }                                                                  \
        }                                                                    \
      }                                                                      \
    }

#pragma unroll 4
    for (int jt = 0; jt < SPANW; jt += 16) {
      int jb = jb0 + jt;
      bf16x8 b = *(const bf16x8*)(hnb + (size_t)(jb + l16)*32 + half*8);
      f32x4 d = __builtin_amdgcn_mfma_f32_16x16x32_bf16(a, b, zero, 0, 0, 0);
      bool h0 = d[0] >= tm0, h1 = d[1] >= tm1, h2 = d[2] >= tm2, h3 = d[3] >= tm3;
      if (__any(h0 | h1 | h2 | h3)) {
        APPB(0, h0) APPB(1, h1) APPB(2, h2) APPB(3, h3)
      }
    }
#undef APPB
  }
  __syncthreads();

  // ---- phase 3: exact fp32 top-6 from LDS hit list, wave per row ----
  {
    int row = r0 + wave;
    int n = min(cntl[wave], CAPL);
    float4 q[4];
#pragma unroll
    for (int m = 0; m < 4; ++m) q[m] = hn4[(size_t)row*4 + m];
    Top6 t; t6_init(t);
    for (int e = lane; e < n; e += 64) {
      int j = hbuf[wave][e];
      if (j != row) {
        float4 cv[4];
#pragma unroll
        for (int m = 0; m < 4; ++m) cv[m] = hn4[(size_t)j*4 + m];
        float sc = dot16_seq(q, cv);
        t6_insert(t, sc, j);
      }
    }
    float osum = 0.f;
    for (int sel = 0; sel < K; ++sel) {
      float cv; int ci;
      t6_best(t, cv, ci);
      float mv = cv; int mi = ci;
#pragma unroll
      for (int m = 1; m < 64; m <<= 1) {
        float ov = __shfl_xor(mv, m);
        int   oi = __shfl_xor(mi, m);
        if (ov > mv || (ov == mv && (unsigned)oi < (unsigned)mi)) { mv = ov; mi = oi; }
      }
      t6_consume(t, mi);
      if (lane == 0) {
        evals[row*K + sel] = mv;
        eidx [row*K + sel] = mi;
        osum += mv;
        atomicAdd(&insum[mi], mv);
        int pos = atomicAdd(&indeg[mi], 1);
        if (pos < CIN) {
          incol[(size_t)mi*CIN + pos] = (unsigned short)row;
          inval[(size_t)mi*CIN + pos] = mv;
        }
      }
    }
    if (lane == 0) ownsum[row] = osum;
  }
}

// ---- DOUT=32 layer: GCN + LN + ReLU + MLP residual, 2 rows/wave.
// SCALED: XWsrc already carries dinv_j -> per-edge coef is cc*v.
// Epilogue writes XWnext PRE-SCALED by dinv_row.
template<int DIN, int NEXTD, bool SCALED>
__global__ __launch_bounds__(256) void k_gpost32(
    const float* __restrict__ XWsrc,
    const int* __restrict__ eidx, const float* __restrict__ evals,
    const unsigned short* __restrict__ incol, const float* __restrict__ inval,
    const int* __restrict__ indeg,
    const float* __restrict__ ownsum, const float* __restrict__ insum,
    const float* __restrict__ gb, const float* __restrict__ lg, const float* __restrict__ lb,
    const float* __restrict__ hprev,
    const float* __restrict__ w0, const float* __restrict__ b0,
    const float* __restrict__ w1, const float* __restrict__ b1,
    const float* __restrict__ Wnext, float* __restrict__ XWnext,
    float* __restrict__ outp, int N) {
  __shared__ float hid[4][2][32];
  int tid = threadIdx.x;
  int lane = tid & 63, wslot = tid >> 6;
  int sub = lane >> 5, ol = lane & 31;
  int row = (blockIdx.x * 4 + wslot) * 2 + sub;

  float rs_i = 0.5f * (ownsum[row] + insum[row]);
  float rn_i = 1.f / (rs_i + 1e-8f);
  float di_i = rsqrtf(fmaxf(1.f + rs_i * rn_i, 1e-12f));
  float cc = 0.5f * di_i * rn_i;
  float acc = (SCALED ? di_i : di_i * di_i) * XWsrc[(size_t)row*32 + ol];
#pragma unroll
  for (int t = 0; t < K; ++t) {
    int j = eidx[row*K + t]; float v = evals[row*K + t];
    float cf;
    if constexpr (SCALED) cf = cc * v;
    else                  cf = cc * v * dinv_of(ownsum[j], insum[j]);
    acc = fmaf(cf, XWsrc[(size_t)j*32 + ol], acc);
  }
  int ne = min(indeg[row], CIN);
  for (int e = 0; e < ne; ++e) {
    int j = incol[(size_t)row*CIN + e]; float v = inval[(size_t)row*CIN + e];
    float cf;
    if constexpr (SCALED) cf = cc * v;
    else                  cf = cc * v * dinv_of(ownsum[j], insum[j]);
    acc = fmaf(cf, XWsrc[(size_t)j*32 + ol], acc);
  }
  float u0 = acc + gb[ol];
  float s = u0;
#pragma unroll
  for (int m = 1; m < 32; m <<= 1) s += __shfl_xor(s, m);
  float mean = s * (1.f/32.f);
  float d0 = u0 - mean;
  float vs = d0*d0;
#pragma unroll
  for (int m = 1; m < 32; m <<= 1) vs += __shfl_xor(vs, m);
  float rstd = rsqrtf(vs * (1.f/32.f) + 1e-5f);
  float t0 = fmaxf(d0*rstd*lg[ol] + lb[ol], 0.f);

  // MLP residual (per-wave LDS; same-wave lockstep -> no barrier)
  float hp[DIN];
#pragma unroll
  for (int d = 0; d < DIN; ++d) hp[d] = hprev[(size_t)row*DIN + d];
  float a = b0[ol];
#pragma unroll
  for (int d = 0; d < DIN; ++d) a = fmaf(hp[d], w0[d*32 + ol], a);
  hid[wslot][sub][ol] = fmaxf(a, 0.f);
  float o = b1[ol];
#pragma unroll
  for (int h = 0; h < 32; ++h) o = fmaf(hid[wslot][sub][h], w1[h*32 + ol], o);
  float hv = t0 + o;
  outp[(size_t)row*32 + ol] = hv;

  // epilogue: XWnext = dinv_row * (h @ Wnext)  (PRE-SCALED for next layer)
  hid[wslot][sub][ol] = hv;
#pragma unroll
  for (int k2 = 0; k2 < NEXTD/32; ++k2) {
    int oc = ol + 32*k2;
    float acc2 = 0.f;
#pragma unroll
    for (int d = 0; d < 32; ++d)
      acc2 = fmaf(hid[wslot][sub][d], Wnext[d*NEXTD + oc], acc2);
    XWnext[(size_t)row*NEXTD + oc] = di_i * acc2;
  }
}

// ---------------- final layer (DOUT=128): pre-scaled XW gather + LDS-staged w1 ----
__global__ __launch_bounds__(256) void k_gpost128(
    const float* __restrict__ XW,     // pre-scaled by dinv_j
    const int* __restrict__ eidx, const float* __restrict__ evals,
    const unsigned short* __restrict__ incol, const float* __restrict__ inval,
    const int* __restrict__ indeg,
    const float* __restrict__ ownsum, const float* __restrict__ insum,
    const float* __restrict__ b, const float* __restrict__ g, const float* __restrict__ bt,
    const float* __restrict__ hprev,
    const float* __restrict__ w0, const float* __restrict__ b0,
    const float* __restrict__ w1, const float* __restrict__ b1,
    float* __restrict__ out, int N) {
  __shared__ float hid_s[4][128];
  __shared__ float w1s[2048];          // 16 h-rows x 128 cols chunk (8 KB)
  int wslot = threadIdx.x >> 6;
  int row   = (blockIdx.x * blockDim.x + threadIdx.x) >> 6;
  int lane  = threadIdx.x & 63;
  int o0 = lane, o1 = lane + 64;

  float rs_i = 0.5f * (ownsum[row] + insum[row]);
  float rn_i = 1.f / (rs_i + 1e-8f);
  float di_i = rsqrtf(fmaxf(1.f + rs_i * rn_i, 1e-12f));
  float cc = 0.5f * di_i * rn_i;
  float acc0 = di_i * XW[(size_t)row*128 + o0];
  float acc1 = di_i * XW[(size_t)row*128 + o1];
#pragma unroll
  for (int t = 0; t < K; ++t) {
    int j = eidx[row*K + t];
    float cf = cc * evals[row*K + t];
    acc0 = fmaf(cf, XW[(size_t)j*128 + o0], acc0);
    acc1 = fmaf(cf, XW[(size_t)j*128 + o1], acc1);
  }
  int ne = min(indeg[row], CIN);
  for (int e = 0; e < ne; ++e) {
    int j = incol[(size_t)row*CIN + e];
    float cf = cc * inval[(size_t)row*CIN + e];
    acc0 = fmaf(cf, XW[(size_t)j*128 + o0], acc0);
    acc1 = fmaf(cf, XW[(size_t)j*128 + o1], acc1);
  }
  float u0 = acc0 + b[o0];
  float u1 = acc1 + b[o1];

  float s = u0 + u1;
#pragma unroll
  for (int m = 1; m < 64; m <<= 1) s += __shfl_xor(s, m);
  float mean = s * (1.f/128.f);
  float d0 = u0 - mean, d1 = u1 - mean;
  float vs = d0*d0 + d1*d1;
#pragma unroll
  for (int m = 1; m < 64; m <<= 1) vs += __shfl_xor(vs, m);
  float rstd = rsqrtf(vs * (1.f/128.f) + 1e-5f);
  float t0 = fmaxf(d0*rstd*g[o0] + bt[o0], 0.f);
  float t1 = fmaxf(d1*rstd*g[o1] + bt[o1], 0.f);

  float hp[32];
#pragma unroll
  for (int d = 0; d < 32; ++d) hp[d] = hprev[(size_t)row*32 + d];
  {
    float a = b0[o0];
#pragma unroll
    for (int d = 0; d < 32; ++d) a = fmaf(hp[d], w0[d*128 + o0], a);
    hid_s[wslot][o0] = fmaxf(a, 0.f);
    float a1 = b0[o1];
#pragma unroll
    for (int d = 0; d < 32; ++d) a1 = fmaf(hp[d], w0[d*128 + o1], a1);
    hid_s[wslot][o1] = fmaxf(a1, 0.f);
  }

  // out = hid @ w1 with w1 staged through LDS in 8 chunks of 16 rows.
  float r0=0.f, r1=0.f, r2=0.f, r3=0.f, q0=0.f, q1=0.f, q2=0.f, q3=0.f;
  for (int c = 0; c < 8; ++c) {
    __syncthreads();
    {
      const float4* src = (const float4*)(w1 + c*2048);
      float4* dst = (float4*)w1s;
      dst[threadIdx.x]       = src[threadIdx.x];
      dst[threadIdx.x + 256] = src[threadIdx.x + 256];
    }
    __syncthreads();
    int hb = c*16;
#pragma unroll
    for (int hh = 0; hh < 16; hh += 4) {
      float h0 = hid_s[wslot][hb+hh+0], h1 = hid_s[wslot][hb+hh+1],
            h2 = hid_s[wslot][hb+hh+2], h3 = hid_s[wslot][hb+hh+3];
      r0 = fmaf(h0, w1s[(hh+0)*128 + o0], r0); q0 = fmaf(h0, w1s[(hh+0)*128 + o1], q0);
      r1 = fmaf(h1, w1s[(hh+1)*128 + o0], r1); q1 = fmaf(h1, w1s[(hh+1)*128 + o1], q1);
      r2 = fmaf(h2, w1s[(hh+2)*128 + o0], r2); q2 = fmaf(h2, w1s[(hh+2)*128 + o1], q2);
      r3 = fmaf(h3, w1s[(hh+3)*128 + o0], r3); q3 = fmaf(h3, w1s[(hh+3)*128 + o1], q3);
    }
  }
  out[(size_t)row*128 + o0] = t0 + b1[o0] + ((r0 + r1) + (r2 + r3));
  out[(size_t)row*128 + o1] = t1 + b1[o1] + ((q0 + q1) + (q2 + q3));
}

extern "C" void kernel_launch(void* const* d_in, const int* in_sizes, int n_in,
                              void* d_out, int out_size, void* d_ws, size_t ws_size,
                              hipStream_t stream) {
  const float* x    = (const float*)d_in[0];
  const float* Wp   = (const float*)d_in[1];
  const float* bp   = (const float*)d_in[2];
  const float* gw0  = (const float*)d_in[3];
  const float* gb0  = (const float*)d_in[4];
  const float* gw1  = (const float*)d_in[5];
  const float* gb1  = (const float*)d_in[6];
  const float* gw2  = (const float*)d_in[7];
  const float* gb2  = (const float*)d_in[8];
  const float* lg0  = (const float*)d_in[9];
  const float* lb0  = (const float*)d_in[10];
  const float* lg1  = (const float*)d_in[11];
  const float* lb1  = (const float*)d_in[12];
  const float* lg2  = (const float*)d_in[13];
  const float* lb2  = (const float*)d_in[14];
  const float* riw0 = (const float*)d_in[15];
  const float* rib0 = (const float*)d_in[16];
  const float* riw1 = (const float*)d_in[17];
  const float* rib1 = (const float*)d_in[18];
  const float* rhw0 = (const float*)d_in[19];
  const float* rhb0 = (const float*)d_in[20];
  const float* rhw1 = (const float*)d_in[21];
  const float* rhb1 = (const float*)d_in[22];
  const float* row0 = (const float*)d_in[23];
  const float* rob0 = (const float*)d_in[24];
  const float* row1 = (const float*)d_in[25];
  const float* rob1 = (const float*)d_in[26];
  int N = in_sizes[0] / D_IN;   // 8192
  float* out = (float*)d_out;

  char* ws = (char*)d_ws;
  size_t off = 0;
  auto alloc = [&](size_t bytes) -> void* {
    void* p = ws + off;
    off += (bytes + 255) & ~(size_t)255;
    return p;
  };
  float* hn      = (float*)alloc((size_t)N * HP * 4);
  float* evals   = (float*)alloc((size_t)N * K * 4);
  int*   eidx    = (int*)  alloc((size_t)N * K * 4);
  float* ownsum  = (float*)alloc((size_t)N * 4);
  float* insum   = (float*)alloc((size_t)N * 4);
  int*   indeg   = (int*)  alloc((size_t)N * 4);
  float* XWa     = (float*)alloc((size_t)N * 128 * 4);
  float* XWb     = (float*)alloc((size_t)N * 32 * 4);
  float* h1      = (float*)alloc((size_t)N * 32 * 4);
  float* h2      = (float*)alloc((size_t)N * 32 * 4);
  float* tau     = (float*)alloc((size_t)N * 4);
  short* hnb     = (short*)alloc((size_t)N * 32 * 2);
  unsigned short* incol = (unsigned short*)alloc((size_t)N * CIN * 2);
  float* inval   = (float*)alloc((size_t)N * CIN * 4);
  (void)ws_size; (void)n_in; (void)out_size;

  const int B = 256;
  hipLaunchKernelGGL(k_proj, dim3((N + B - 1) / B), dim3(B), 0, stream,
                     x, Wp, bp, gw0, hn, hnb, XWa, insum, indeg, N);
  // threshold: separate 256-thread kernel (sane codegen)
  hipLaunchKernelGGL(k_thresh, dim3(N / 4), dim3(B), 0, stream, hn, tau, N);
  // fused MFMA scan + exact top-6: 512 blocks x 1024 threads
  hipLaunchKernelGGL(k_scan23, dim3(N / 16), dim3(1024), 0, stream,
                     hn, hnb, tau, evals, eidx, ownsum, insum, indeg, incol, inval, N);

  // layer 0: XWa unscaled -> h1; epilogue XWb = dinv * (h1 @ gw1)
  hipLaunchKernelGGL((k_gpost32<20, 32, false>), dim3(N / 8), dim3(B), 0, stream,
                     XWa, eidx, evals, incol, inval, indeg, ownsum, insum,
                     gb0, lg0, lb0, x, riw0, rib0, riw1, rib1, gw1, XWb, h1, N);
  // layer 1: XWb pre-scaled -> h2; epilogue XWa = dinv * (h2 @ gw2)
  hipLaunchKernelGGL((k_gpost32<32, 128, true>), dim3(N / 8), dim3(B), 0, stream,
                     XWb, eidx, evals, incol, inval, indeg, ownsum, insum,
                     gb1, lg1, lb1, h1, rhw0, rhb0, rhw1, rhb1, gw2, XWa, h2, N);
  // layer 2: XWa pre-scaled -> out
  hipLaunchKernelGGL(k_gpost128, dim3(N / 4), dim3(B), 0, stream,
                     XWa, eidx, evals, incol, inval, indeg, ownsum, insum,
                     gb2, lg2, lb2, h2, row0, rob0, row1, rob1, out, N);
}

// Round 28
// 139.250 us; speedup vs baseline: 1.2238x; 1.0582x over previous
//
#include <hip/hip_runtime.h>

constexpr int D_IN = 20;   // input feature dim
constexpr int HP   = 16;   // projection dim
constexpr int K    = 6;    // neighbors
constexpr int SAMP = 512;  // threshold sample size
constexpr int CAPL = 384;  // per-row LDS hit-buffer capacity (mean ~105)
constexpr int CIN  = 128;  // per-row in-edge slots
constexpr float MARGIN = 0.01f;  // bf16 dot error <= 2^-8 ~ 0.004; 2.5x margin

typedef __attribute__((ext_vector_type(8))) short bf16x8;
typedef __attribute__((ext_vector_type(4))) float f32x4;

// Sequential fmaf dot — MUST be bit-identical across thresh/final.
__device__ __forceinline__ float dot16_seq(const float4* q, const float4* c) {
  float s = 0.f;
#pragma unroll
  for (int m = 0; m < 4; ++m) {
    s = fmaf(q[m].x, c[m].x, s);
    s = fmaf(q[m].y, c[m].y, s);
    s = fmaf(q[m].z, c[m].z, s);
    s = fmaf(q[m].w, c[m].w, s);
  }
  return s;
}

// round-to-nearest-even f32 -> bf16 bits
__device__ __forceinline__ short f2bf(float f) {
  unsigned u = __float_as_uint(f);
  unsigned r = (u + 0x7fffu + ((u >> 16) & 1u)) >> 16;
  return (short)r;
}

__device__ __forceinline__ float dinv_of(float own, float ins) {
  float rs = 0.5f * (own + ins);
  float rn = 1.f / (rs + 1e-8f);
  return rsqrtf(fmaxf(1.f + rs * rn, 1e-12f));
}

// ---- projection + row-normalize + bf16 copy + XW0 + counter zeroing ----
__global__ void k_proj(const float* __restrict__ x, const float* __restrict__ Wp,
                       const float* __restrict__ bp, const float* __restrict__ gw0,
                       float* __restrict__ hn, short* __restrict__ hnb,
                       float* __restrict__ XW0,
                       float* __restrict__ insum, int* __restrict__ indeg, int N) {
  int i = blockIdx.x * blockDim.x + threadIdx.x;
  if (i >= N) return;
  insum[i] = 0.f; indeg[i] = 0;
  float xr[D_IN];
#pragma unroll
  for (int d = 0; d < D_IN; ++d) xr[d] = x[i*D_IN + d];
  float hv[HP];
  float nrm2 = 0.f;
#pragma unroll
  for (int h = 0; h < HP; ++h) {
    float a = bp[h];
#pragma unroll
    for (int d = 0; d < D_IN; ++d) a += xr[d] * Wp[d*HP + h];
    hv[h] = a;
    nrm2 += a * a;
  }
  float inv = 1.f / fmaxf(sqrtf(nrm2), 1e-12f);
#pragma unroll
  for (int h = 0; h < HP; ++h) {
    float v = hv[h] * inv;
    hn[i*HP + h] = v;
    hnb[(size_t)i*32 + h] = f2bf(v);
  }
#pragma unroll
  for (int h = 0; h < HP; ++h) hnb[(size_t)i*32 + 16 + h] = 0;
#pragma unroll
  for (int oc = 0; oc < 32; ++oc) {
    float a = 0.f;
#pragma unroll
    for (int d = 0; d < D_IN; ++d) a += xr[d] * gw0[d*32 + oc];
    XW0[(size_t)i*32 + oc] = a;
  }
}

// ---------------- per-lane top-6 in NAMED registers ----
struct Top6 { float v0,v1,v2,v3,v4,v5; int i0,i1,i2,i3,i4,i5; };

__device__ __forceinline__ void t6_init(Top6& t) {
  t.v0=t.v1=t.v2=t.v3=t.v4=t.v5=-1e30f;
  t.i0=t.i1=t.i2=t.i3=t.i4=t.i5=-1;
}

#define T6_SWAP(a,b,ia,ib) { float tv=a; a=b; b=tv; int ti=ia; ia=ib; ib=ti; }

__device__ __forceinline__ void t6_insert(Top6& t, float s, int c) {
  if (s > t.v5) {
    t.v5 = s; t.i5 = c;
    if (t.v5 > t.v4) { T6_SWAP(t.v4, t.v5, t.i4, t.i5); }
    if (t.v4 > t.v3) { T6_SWAP(t.v3, t.v4, t.i3, t.i4); }
    if (t.v3 > t.v2) { T6_SWAP(t.v2, t.v3, t.i2, t.i3); }
    if (t.v2 > t.v1) { T6_SWAP(t.v1, t.v2, t.i1, t.i2); }
    if (t.v1 > t.v0) { T6_SWAP(t.v0, t.v1, t.i0, t.i1); }
  }
}

__device__ __forceinline__ void t6_best(const Top6& t, float& cv, int& ci) {
  cv = t.v0; ci = t.i0;
  if (t.v1 > cv || (t.v1 == cv && (unsigned)t.i1 < (unsigned)ci)) { cv = t.v1; ci = t.i1; }
  if (t.v2 > cv || (t.v2 == cv && (unsigned)t.i2 < (unsigned)ci)) { cv = t.v2; ci = t.i2; }
  if (t.v3 > cv || (t.v3 == cv && (unsigned)t.i3 < (unsigned)ci)) { cv = t.v3; ci = t.i3; }
  if (t.v4 > cv || (t.v4 == cv && (unsigned)t.i4 < (unsigned)ci)) { cv = t.v4; ci = t.i4; }
  if (t.v5 > cv || (t.v5 == cv && (unsigned)t.i5 < (unsigned)ci)) { cv = t.v5; ci = t.i5; }
}

__device__ __forceinline__ void t6_consume(Top6& t, int mi) {
  if (t.i0 == mi) t.v0 = -1e30f;
  if (t.i1 == mi) t.v1 = -1e30f;
  if (t.i2 == mi) t.v2 = -1e30f;
  if (t.i3 == mi) t.v3 = -1e30f;
  if (t.i4 == mi) t.v4 = -1e30f;
  if (t.i5 == mi) t.v5 = -1e30f;
}

// ---------------- threshold pass: exact 6th-largest over SAMP-sample, wave per row
__global__ __launch_bounds__(256) void k_thresh(const float* __restrict__ hn,
                                                float* __restrict__ tau, int N) {
  int wave = threadIdx.x >> 6, lane = threadIdx.x & 63;
  int row = blockIdx.x * 4 + wave;
  const float4* hn4 = (const float4*)hn;
  float4 q[4];
#pragma unroll
  for (int m = 0; m < 4; ++m) q[m] = hn4[(size_t)row*4 + m];
  Top6 t; t6_init(t);
#pragma unroll
  for (int k = 0; k < SAMP/64; ++k) {
    int c = lane + 64*k;
    if (c != row) {
      float4 cv[4];
#pragma unroll
      for (int m = 0; m < 4; ++m) cv[m] = hn4[(size_t)c*4 + m];
      float s = dot16_seq(q, cv);
      t6_insert(t, s, c);
    }
  }
  float last = -1e30f;
  for (int sel = 0; sel < K; ++sel) {
    float cv; int ci;
    t6_best(t, cv, ci);
    float mv = cv; int mi = ci;
#pragma unroll
    for (int m = 1; m < 64; m <<= 1) {
      float ov = __shfl_xor(mv, m);
      int   oi = __shfl_xor(mi, m);
      if (ov > mv || (ov == mv && (unsigned)oi < (unsigned)mi)) { mv = ov; mi = oi; }
    }
    t6_consume(t, mi);
    last = mv;
  }
  if (lane == 0) tau[row] = last;
}

// ---- FUSED phases 2+3: MFMA scan (LDS hit buffers, PARALLEL hit writes) + top-6 --
// 512 blocks x 1024 threads; tau read from global.
__global__ __launch_bounds__(1024) void k_scan23(
    const float* __restrict__ hn, const short* __restrict__ hnb,
    const float* __restrict__ tau,
    float* __restrict__ evals, int* __restrict__ eidx,
    float* __restrict__ ownsum, float* insum, int* indeg,
    unsigned short* __restrict__ incol, float* __restrict__ inval, int N) {
  __shared__ unsigned short hbuf[16][CAPL];   // 12 KB
  __shared__ int cntl[16];
  int tid = threadIdx.x;
  int wave = tid >> 6, lane = tid & 63;
  int r0 = blockIdx.x * 16;
  const float4* hn4 = (const float4*)hn;

  if (tid < 16) cntl[tid] = 0;
  __syncthreads();

  // ---- phase 2: MFMA scan; hits written in parallel (leader atomic + shfl base,
  // ---- each hitting lane writes its own slot via prefix-popc) ----
  {
    int half = lane >> 4;            // 0..3
    int l16  = lane & 15;
    int gleader = half << 4;         // lane index of this 16-group's leader
    unsigned below = (1u << l16) - 1u;
    bf16x8 a = *(const bf16x8*)(hnb + (size_t)(r0 + l16)*32 + half*8);
    float4 t4 = *(const float4*)(tau + r0 + half*4);
    float tm0 = t4.x - MARGIN, tm1 = t4.y - MARGIN,
          tm2 = t4.z - MARGIN, tm3 = t4.w - MARGIN;
    f32x4 zero = {0.f, 0.f, 0.f, 0.f};
    const int SPANW = N / 16;        // 512 cands per wave
    int jb0 = wave * SPANW;

#define APPB(R, COND)                                                        \
    {                                                                        \
      bool h = (COND);                                                       \
      unsigned long long mr = __ballot(h);                                   \
      unsigned mask = (unsigned)(mr >> (16*half)) & 0xFFFFu;                 \
      if (mask) {                                                            \
        int rl = 4*half + (R);                                               \
        int base = 0;                                                        \
        if (l16 == 0) base = atomicAdd(&cntl[rl], __popc(mask));             \
        base = __shfl(base, gleader);                                        \
        if (h) {                                                             \
          int mypos = base + __popc(mask & below);                           \
          if (mypos < CAPL) hbuf[rl][mypos] = (unsigned short)(jb + l16);    \
        }                                                                    \
      }                                                                      \
    }

#pragma unroll 4
    for (int jt = 0; jt < SPANW; jt += 16) {
      int jb = jb0 + jt;
      bf16x8 b = *(const bf16x8*)(hnb + (size_t)(jb + l16)*32 + half*8);
      f32x4 d = __builtin_amdgcn_mfma_f32_16x16x32_bf16(a, b, zero, 0, 0, 0);
      bool h0 = d[0] >= tm0, h1 = d[1] >= tm1, h2 = d[2] >= tm2, h3 = d[3] >= tm3;
      if (__any(h0 | h1 | h2 | h3)) {
        APPB(0, h0) APPB(1, h1) APPB(2, h2) APPB(3, h3)
      }
    }
#undef APPB
  }
  __syncthreads();

  // ---- phase 3: exact fp32 top-6 from LDS hit list, wave per row ----
  {
    int row = r0 + wave;
    int n = min(cntl[wave], CAPL);
    float4 q[4];
#pragma unroll
    for (int m = 0; m < 4; ++m) q[m] = hn4[(size_t)row*4 + m];
    Top6 t; t6_init(t);
    for (int e = lane; e < n; e += 64) {
      int j = hbuf[wave][e];
      if (j != row) {
        float4 cv[4];
#pragma unroll
        for (int m = 0; m < 4; ++m) cv[m] = hn4[(size_t)j*4 + m];
        float sc = dot16_seq(q, cv);
        t6_insert(t, sc, j);
      }
    }
    float osum = 0.f;
    for (int sel = 0; sel < K; ++sel) {
      float cv; int ci;
      t6_best(t, cv, ci);
      float mv = cv; int mi = ci;
#pragma unroll
      for (int m = 1; m < 64; m <<= 1) {
        float ov = __shfl_xor(mv, m);
        int   oi = __shfl_xor(mi, m);
        if (ov > mv || (ov == mv && (unsigned)oi < (unsigned)mi)) { mv = ov; mi = oi; }
      }
      t6_consume(t, mi);
      if (lane == 0) {
        evals[row*K + sel] = mv;
        eidx [row*K + sel] = mi;
        osum += mv;
        atomicAdd(&insum[mi], mv);
        int pos = atomicAdd(&indeg[mi], 1);
        if (pos < CIN) {
          incol[(size_t)mi*CIN + pos] = (unsigned short)row;
          inval[(size_t)mi*CIN + pos] = mv;
        }
      }
    }
    if (lane == 0) ownsum[row] = osum;
  }
}

// ---- DOUT=32 layer: GCN + LN + ReLU + MLP residual, 2 rows/wave.
// SCALED: XWsrc already carries dinv_j -> per-edge coef is cc*v.
// Epilogue writes XWnext PRE-SCALED by dinv_row.
template<int DIN, int NEXTD, bool SCALED>
__global__ __launch_bounds__(256) void k_gpost32(
    const float* __restrict__ XWsrc,
    const int* __restrict__ eidx, const float* __restrict__ evals,
    const unsigned short* __restrict__ incol, const float* __restrict__ inval,
    const int* __restrict__ indeg,
    const float* __restrict__ ownsum, const float* __restrict__ insum,
    const float* __restrict__ gb, const float* __restrict__ lg, const float* __restrict__ lb,
    const float* __restrict__ hprev,
    const float* __restrict__ w0, const float* __restrict__ b0,
    const float* __restrict__ w1, const float* __restrict__ b1,
    const float* __restrict__ Wnext, float* __restrict__ XWnext,
    float* __restrict__ outp, int N) {
  __shared__ float hid[4][2][32];
  int tid = threadIdx.x;
  int lane = tid & 63, wslot = tid >> 6;
  int sub = lane >> 5, ol = lane & 31;
  int row = (blockIdx.x * 4 + wslot) * 2 + sub;

  float rs_i = 0.5f * (ownsum[row] + insum[row]);
  float rn_i = 1.f / (rs_i + 1e-8f);
  float di_i = rsqrtf(fmaxf(1.f + rs_i * rn_i, 1e-12f));
  float cc = 0.5f * di_i * rn_i;
  float acc = (SCALED ? di_i : di_i * di_i) * XWsrc[(size_t)row*32 + ol];
#pragma unroll
  for (int t = 0; t < K; ++t) {
    int j = eidx[row*K + t]; float v = evals[row*K + t];
    float cf;
    if constexpr (SCALED) cf = cc * v;
    else                  cf = cc * v * dinv_of(ownsum[j], insum[j]);
    acc = fmaf(cf, XWsrc[(size_t)j*32 + ol], acc);
  }
  int ne = min(indeg[row], CIN);
  for (int e = 0; e < ne; ++e) {
    int j = incol[(size_t)row*CIN + e]; float v = inval[(size_t)row*CIN + e];
    float cf;
    if constexpr (SCALED) cf = cc * v;
    else                  cf = cc * v * dinv_of(ownsum[j], insum[j]);
    acc = fmaf(cf, XWsrc[(size_t)j*32 + ol], acc);
  }
  float u0 = acc + gb[ol];
  float s = u0;
#pragma unroll
  for (int m = 1; m < 32; m <<= 1) s += __shfl_xor(s, m);
  float mean = s * (1.f/32.f);
  float d0 = u0 - mean;
  float vs = d0*d0;
#pragma unroll
  for (int m = 1; m < 32; m <<= 1) vs += __shfl_xor(vs, m);
  float rstd = rsqrtf(vs * (1.f/32.f) + 1e-5f);
  float t0 = fmaxf(d0*rstd*lg[ol] + lb[ol], 0.f);

  // MLP residual (per-wave LDS; same-wave lockstep -> no barrier)
  float hp[DIN];
#pragma unroll
  for (int d = 0; d < DIN; ++d) hp[d] = hprev[(size_t)row*DIN + d];
  float a = b0[ol];
#pragma unroll
  for (int d = 0; d < DIN; ++d) a = fmaf(hp[d], w0[d*32 + ol], a);
  hid[wslot][sub][ol] = fmaxf(a, 0.f);
  float o = b1[ol];
#pragma unroll
  for (int h = 0; h < 32; ++h) o = fmaf(hid[wslot][sub][h], w1[h*32 + ol], o);
  float hv = t0 + o;
  outp[(size_t)row*32 + ol] = hv;

  // epilogue: XWnext = dinv_row * (h @ Wnext)  (PRE-SCALED for next layer)
  hid[wslot][sub][ol] = hv;
#pragma unroll
  for (int k2 = 0; k2 < NEXTD/32; ++k2) {
    int oc = ol + 32*k2;
    float acc2 = 0.f;
#pragma unroll
    for (int d = 0; d < 32; ++d)
      acc2 = fmaf(hid[wslot][sub][d], Wnext[d*NEXTD + oc], acc2);
    XWnext[(size_t)row*NEXTD + oc] = di_i * acc2;
  }
}

// ---------------- final layer (DOUT=128): pre-scaled XW gather + LDS-staged w1 ----
__global__ __launch_bounds__(256) void k_gpost128(
    const float* __restrict__ XW,     // pre-scaled by dinv_j
    const int* __restrict__ eidx, const float* __restrict__ evals,
    const unsigned short* __restrict__ incol, const float* __restrict__ inval,
    const int* __restrict__ indeg,
    const float* __restrict__ ownsum, const float* __restrict__ insum,
    const float* __restrict__ b, const float* __restrict__ g, const float* __restrict__ bt,
    const float* __restrict__ hprev,
    const float* __restrict__ w0, const float* __restrict__ b0,
    const float* __restrict__ w1, const float* __restrict__ b1,
    float* __restrict__ out, int N) {
  __shared__ float hid_s[4][128];
  __shared__ float w1s[2048];          // 16 h-rows x 128 cols chunk (8 KB)
  int wslot = threadIdx.x >> 6;
  int row   = (blockIdx.x * blockDim.x + threadIdx.x) >> 6;
  int lane  = threadIdx.x & 63;
  int o0 = lane, o1 = lane + 64;

  float rs_i = 0.5f * (ownsum[row] + insum[row]);
  float rn_i = 1.f / (rs_i + 1e-8f);
  float di_i = rsqrtf(fmaxf(1.f + rs_i * rn_i, 1e-12f));
  float cc = 0.5f * di_i * rn_i;
  float acc0 = di_i * XW[(size_t)row*128 + o0];
  float acc1 = di_i * XW[(size_t)row*128 + o1];
#pragma unroll
  for (int t = 0; t < K; ++t) {
    int j = eidx[row*K + t];
    float cf = cc * evals[row*K + t];
    acc0 = fmaf(cf, XW[(size_t)j*128 + o0], acc0);
    acc1 = fmaf(cf, XW[(size_t)j*128 + o1], acc1);
  }
  int ne = min(indeg[row], CIN);
  for (int e = 0; e < ne; ++e) {
    int j = incol[(size_t)row*CIN + e];
    float cf = cc * inval[(size_t)row*CIN + e];
    acc0 = fmaf(cf, XW[(size_t)j*128 + o0], acc0);
    acc1 = fmaf(cf, XW[(size_t)j*128 + o1], acc1);
  }
  float u0 = acc0 + b[o0];
  float u1 = acc1 + b[o1];

  float s = u0 + u1;
#pragma unroll
  for (int m = 1; m < 64; m <<= 1) s += __shfl_xor(s, m);
  float mean = s * (1.f/128.f);
  float d0 = u0 - mean, d1 = u1 - mean;
  float vs = d0*d0 + d1*d1;
#pragma unroll
  for (int m = 1; m < 64; m <<= 1) vs += __shfl_xor(vs, m);
  float rstd = rsqrtf(vs * (1.f/128.f) + 1e-5f);
  float t0 = fmaxf(d0*rstd*g[o0] + bt[o0], 0.f);
  float t1 = fmaxf(d1*rstd*g[o1] + bt[o1], 0.f);

  float hp[32];
#pragma unroll
  for (int d = 0; d < 32; ++d) hp[d] = hprev[(size_t)row*32 + d];
  {
    float a = b0[o0];
#pragma unroll
    for (int d = 0; d < 32; ++d) a = fmaf(hp[d], w0[d*128 + o0], a);
    hid_s[wslot][o0] = fmaxf(a, 0.f);
    float a1 = b0[o1];
#pragma unroll
    for (int d = 0; d < 32; ++d) a1 = fmaf(hp[d], w0[d*128 + o1], a1);
    hid_s[wslot][o1] = fmaxf(a1, 0.f);
  }

  // out = hid @ w1 with w1 staged through LDS in 8 chunks of 16 rows.
  float r0=0.f, r1=0.f, r2=0.f, r3=0.f, q0=0.f, q1=0.f, q2=0.f, q3=0.f;
  for (int c = 0; c < 8; ++c) {
    __syncthreads();
    {
      const float4* src = (const float4*)(w1 + c*2048);
      float4* dst = (float4*)w1s;
      dst[threadIdx.x]       = src[threadIdx.x];
      dst[threadIdx.x + 256] = src[threadIdx.x + 256];
    }
    __syncthreads();
    int hb = c*16;
#pragma unroll
    for (int hh = 0; hh < 16; hh += 4) {
      float h0 = hid_s[wslot][hb+hh+0], h1 = hid_s[wslot][hb+hh+1],
            h2 = hid_s[wslot][hb+hh+2], h3 = hid_s[wslot][hb+hh+3];
      r0 = fmaf(h0, w1s[(hh+0)*128 + o0], r0); q0 = fmaf(h0, w1s[(hh+0)*128 + o1], q0);
      r1 = fmaf(h1, w1s[(hh+1)*128 + o0], r1); q1 = fmaf(h1, w1s[(hh+1)*128 + o1], q1);
      r2 = fmaf(h2, w1s[(hh+2)*128 + o0], r2); q2 = fmaf(h2, w1s[(hh+2)*128 + o1], q2);
      r3 = fmaf(h3, w1s[(hh+3)*128 + o0], r3); q3 = fmaf(h3, w1s[(hh+3)*128 + o1], q3);
    }
  }
  out[(size_t)row*128 + o0] = t0 + b1[o0] + ((r0 + r1) + (r2 + r3));
  out[(size_t)row*128 + o1] = t1 + b1[o1] + ((q0 + q1) + (q2 + q3));
}

extern "C" void kernel_launch(void* const* d_in, const int* in_sizes, int n_in,
                              void* d_out, int out_size, void* d_ws, size_t ws_size,
                              hipStream_t stream) {
  const float* x    = (const float*)d_in[0];
  const float* Wp   = (const float*)d_in[1];
  const float* bp   = (const float*)d_in[2];
  const float* gw0  = (const float*)d_in[3];
  const float* gb0  = (const float*)d_in[4];
  const float* gw1  = (const float*)d_in[5];
  const float* gb1  = (const float*)d_in[6];
  const float* gw2  = (const float*)d_in[7];
  const float* gb2  = (const float*)d_in[8];
  const float* lg0  = (const float*)d_in[9];
  const float* lb0  = (const float*)d_in[10];
  const float* lg1  = (const float*)d_in[11];
  const float* lb1  = (const float*)d_in[12];
  const float* lg2  = (const float*)d_in[13];
  const float* lb2  = (const float*)d_in[14];
  const float* riw0 = (const float*)d_in[15];
  const float* rib0 = (const float*)d_in[16];
  const float* riw1 = (const float*)d_in[17];
  const float* rib1 = (const float*)d_in[18];
  const float* rhw0 = (const float*)d_in[19];
  const float* rhb0 = (const float*)d_in[20];
  const float* rhw1 = (const float*)d_in[21];
  const float* rhb1 = (const float*)d_in[22];
  const float* row0 = (const float*)d_in[23];
  const float* rob0 = (const float*)d_in[24];
  const float* row1 = (const float*)d_in[25];
  const float* rob1 = (const float*)d_in[26];
  int N = in_sizes[0] / D_IN;   // 8192
  float* out = (float*)d_out;

  char* ws = (char*)d_ws;
  size_t off = 0;
  auto alloc = [&](size_t bytes) -> void* {
    void* p = ws + off;
    off += (bytes + 255) & ~(size_t)255;
    return p;
  };
  float* hn      = (float*)alloc((size_t)N * HP * 4);
  float* evals   = (float*)alloc((size_t)N * K * 4);
  int*   eidx    = (int*)  alloc((size_t)N * K * 4);
  float* ownsum  = (float*)alloc((size_t)N * 4);
  float* insum   = (float*)alloc((size_t)N * 4);
  int*   indeg   = (int*)  alloc((size_t)N * 4);
  float* XWa     = (float*)alloc((size_t)N * 128 * 4);
  float* XWb     = (float*)alloc((size_t)N * 32 * 4);
  float* h1      = (float*)alloc((size_t)N * 32 * 4);
  float* h2      = (float*)alloc((size_t)N * 32 * 4);
  float* tau     = (float*)alloc((size_t)N * 4);
  short* hnb     = (short*)alloc((size_t)N * 32 * 2);
  unsigned short* incol = (unsigned short*)alloc((size_t)N * CIN * 2);
  float* inval   = (float*)alloc((size_t)N * CIN * 4);
  (void)ws_size; (void)n_in; (void)out_size;

  const int B = 256;
  hipLaunchKernelGGL(k_proj, dim3((N + B - 1) / B), dim3(B), 0, stream,
                     x, Wp, bp, gw0, hn, hnb, XWa, insum, indeg, N);
  hipLaunchKernelGGL(k_thresh, dim3(N / 4), dim3(B), 0, stream, hn, tau, N);
  hipLaunchKernelGGL(k_scan23, dim3(N / 16), dim3(1024), 0, stream,
                     hn, hnb, tau, evals, eidx, ownsum, insum, indeg, incol, inval, N);

  // layer 0: XWa unscaled -> h1; epilogue XWb = dinv * (h1 @ gw1)
  hipLaunchKernelGGL((k_gpost32<20, 32, false>), dim3(N / 8), dim3(B), 0, stream,
                     XWa, eidx, evals, incol, inval, indeg, ownsum, insum,
                     gb0, lg0, lb0, x, riw0, rib0, riw1, rib1, gw1, XWb, h1, N);
  // layer 1: XWb pre-scaled -> h2; epilogue XWa = dinv * (h2 @ gw2)
  hipLaunchKernelGGL((k_gpost32<32, 128, true>), dim3(N / 8), dim3(B), 0, stream,
                     XWb, eidx, evals, incol, inval, indeg, ownsum, insum,
                     gb1, lg1, lb1, h1, rhw0, rhb0, rhw1, rhb1, gw2, XWa, h2, N);
  // layer 2: XWa pre-scaled -> out
  hipLaunchKernelGGL(k_gpost128, dim3(N / 4), dim3(B), 0, stream,
                     XWa, eidx, evals, incol, inval, indeg, ownsum, insum,
                     gb2, lg2, lb2, h2, row0, rob0, row1, rob1, out, N);
}

// Round 29
// 137.549 us; speedup vs baseline: 1.2390x; 1.0124x over previous
//
#include <hip/hip_runtime.h>

constexpr int D_IN = 20;   // input feature dim
constexpr int HP   = 16;   // projection dim
constexpr int K    = 6;    // neighbors
constexpr int SAMP = 512;  // threshold sample size
constexpr int CAPL = 384;  // per-row LDS hit-buffer capacity (mean ~105)
constexpr int CIN  = 128;  // per-row in-edge slots
constexpr float MARGIN = 0.01f;  // bf16 dot error <= 2^-8 ~ 0.004; 2.5x margin

typedef __attribute__((ext_vector_type(8))) short bf16x8;
typedef __attribute__((ext_vector_type(4))) float f32x4;

// Sequential fmaf dot — MUST be bit-identical across thresh/final.
__device__ __forceinline__ float dot16_seq(const float4* q, const float4* c) {
  float s = 0.f;
#pragma unroll
  for (int m = 0; m < 4; ++m) {
    s = fmaf(q[m].x, c[m].x, s);
    s = fmaf(q[m].y, c[m].y, s);
    s = fmaf(q[m].z, c[m].z, s);
    s = fmaf(q[m].w, c[m].w, s);
  }
  return s;
}

// round-to-nearest-even f32 -> bf16 bits
__device__ __forceinline__ short f2bf(float f) {
  unsigned u = __float_as_uint(f);
  unsigned r = (u + 0x7fffu + ((u >> 16) & 1u)) >> 16;
  return (short)r;
}

__device__ __forceinline__ float dinv_of(float own, float ins) {
  float rs = 0.5f * (own + ins);
  float rn = 1.f / (rs + 1e-8f);
  return rsqrtf(fmaxf(1.f + rs * rn, 1e-12f));
}

// ---- projection + row-normalize + bf16 copy + XW0 + counter zeroing ----
__global__ void k_proj(const float* __restrict__ x, const float* __restrict__ Wp,
                       const float* __restrict__ bp, const float* __restrict__ gw0,
                       float* __restrict__ hn, short* __restrict__ hnb,
                       float* __restrict__ XW0,
                       float* __restrict__ insum, int* __restrict__ indeg, int N) {
  int i = blockIdx.x * blockDim.x + threadIdx.x;
  if (i >= N) return;
  insum[i] = 0.f; indeg[i] = 0;
  float xr[D_IN];
#pragma unroll
  for (int d = 0; d < D_IN; ++d) xr[d] = x[i*D_IN + d];
  float hv[HP];
  float nrm2 = 0.f;
#pragma unroll
  for (int h = 0; h < HP; ++h) {
    float a = bp[h];
#pragma unroll
    for (int d = 0; d < D_IN; ++d) a += xr[d] * Wp[d*HP + h];
    hv[h] = a;
    nrm2 += a * a;
  }
  float inv = 1.f / fmaxf(sqrtf(nrm2), 1e-12f);
#pragma unroll
  for (int h = 0; h < HP; ++h) {
    float v = hv[h] * inv;
    hn[i*HP + h] = v;
    hnb[(size_t)i*32 + h] = f2bf(v);
  }
#pragma unroll
  for (int h = 0; h < HP; ++h) hnb[(size_t)i*32 + 16 + h] = 0;
#pragma unroll
  for (int oc = 0; oc < 32; ++oc) {
    float a = 0.f;
#pragma unroll
    for (int d = 0; d < D_IN; ++d) a += xr[d] * gw0[d*32 + oc];
    XW0[(size_t)i*32 + oc] = a;
  }
}

// ---------------- per-lane top-6 in NAMED registers ----
struct Top6 { float v0,v1,v2,v3,v4,v5; int i0,i1,i2,i3,i4,i5; };

__device__ __forceinline__ void t6_init(Top6& t) {
  t.v0=t.v1=t.v2=t.v3=t.v4=t.v5=-1e30f;
  t.i0=t.i1=t.i2=t.i3=t.i4=t.i5=-1;
}

#define T6_SWAP(a,b,ia,ib) { float tv=a; a=b; b=tv; int ti=ia; ia=ib; ib=ti; }

__device__ __forceinline__ void t6_insert(Top6& t, float s, int c) {
  if (s > t.v5) {
    t.v5 = s; t.i5 = c;
    if (t.v5 > t.v4) { T6_SWAP(t.v4, t.v5, t.i4, t.i5); }
    if (t.v4 > t.v3) { T6_SWAP(t.v3, t.v4, t.i3, t.i4); }
    if (t.v3 > t.v2) { T6_SWAP(t.v2, t.v3, t.i2, t.i3); }
    if (t.v2 > t.v1) { T6_SWAP(t.v1, t.v2, t.i1, t.i2); }
    if (t.v1 > t.v0) { T6_SWAP(t.v0, t.v1, t.i0, t.i1); }
  }
}

__device__ __forceinline__ void t6_best(const Top6& t, float& cv, int& ci) {
  cv = t.v0; ci = t.i0;
  if (t.v1 > cv || (t.v1 == cv && (unsigned)t.i1 < (unsigned)ci)) { cv = t.v1; ci = t.i1; }
  if (t.v2 > cv || (t.v2 == cv && (unsigned)t.i2 < (unsigned)ci)) { cv = t.v2; ci = t.i2; }
  if (t.v3 > cv || (t.v3 == cv && (unsigned)t.i3 < (unsigned)ci)) { cv = t.v3; ci = t.i3; }
  if (t.v4 > cv || (t.v4 == cv && (unsigned)t.i4 < (unsigned)ci)) { cv = t.v4; ci = t.i4; }
  if (t.v5 > cv || (t.v5 == cv && (unsigned)t.i5 < (unsigned)ci)) { cv = t.v5; ci = t.i5; }
}

__device__ __forceinline__ void t6_consume(Top6& t, int mi) {
  if (t.i0 == mi) t.v0 = -1e30f;
  if (t.i1 == mi) t.v1 = -1e30f;
  if (t.i2 == mi) t.v2 = -1e30f;
  if (t.i3 == mi) t.v3 = -1e30f;
  if (t.i4 == mi) t.v4 = -1e30f;
  if (t.i5 == mi) t.v5 = -1e30f;
}

// ---------------- threshold pass: exact 6th-largest over SAMP-sample, wave per row
__global__ __launch_bounds__(256) void k_thresh(const float* __restrict__ hn,
                                                float* __restrict__ tau, int N) {
  int wave = threadIdx.x >> 6, lane = threadIdx.x & 63;
  int row = blockIdx.x * 4 + wave;
  const float4* hn4 = (const float4*)hn;
  float4 q[4];
#pragma unroll
  for (int m = 0; m < 4; ++m) q[m] = hn4[(size_t)row*4 + m];
  Top6 t; t6_init(t);
#pragma unroll
  for (int k = 0; k < SAMP/64; ++k) {
    int c = lane + 64*k;
    if (c != row) {
      float4 cv[4];
#pragma unroll
      for (int m = 0; m < 4; ++m) cv[m] = hn4[(size_t)c*4 + m];
      float s = dot16_seq(q, cv);
      t6_insert(t, s, c);
    }
  }
  float last = -1e30f;
  for (int sel = 0; sel < K; ++sel) {
    float cv; int ci;
    t6_best(t, cv, ci);
    float mv = cv; int mi = ci;
#pragma unroll
    for (int m = 1; m < 64; m <<= 1) {
      float ov = __shfl_xor(mv, m);
      int   oi = __shfl_xor(mi, m);
      if (ov > mv || (ov == mv && (unsigned)oi < (unsigned)mi)) { mv = ov; mi = oi; }
    }
    t6_consume(t, mi);
    last = mv;
  }
  if (lane == 0) tau[row] = last;
}

// ---- FUSED phases 2+3: dual-tile MFMA scan (merged hit writes) + exact top-6 ----
// 512 blocks x 1024 threads; tau read from global.
__global__ __launch_bounds__(1024) void k_scan23(
    const float* __restrict__ hn, const short* __restrict__ hnb,
    const float* __restrict__ tau,
    float* __restrict__ evals, int* __restrict__ eidx,
    float* __restrict__ ownsum, float* insum, int* indeg,
    unsigned short* __restrict__ incol, float* __restrict__ inval, int N) {
  __shared__ unsigned short hbuf[16][CAPL];   // 12 KB
  __shared__ int cntl[16];
  int tid = threadIdx.x;
  int wave = tid >> 6, lane = tid & 63;
  int r0 = blockIdx.x * 16;
  const float4* hn4 = (const float4*)hn;

  if (tid < 16) cntl[tid] = 0;
  __syncthreads();

  // ---- phase 2: dual-tile MFMA scan; per row-group one atomic covers 2 tiles ----
  {
    int half = lane >> 4;            // 0..3
    int l16  = lane & 15;
    int gleader = half << 4;         // lane index of this 16-group's leader
    unsigned below = (1u << l16) - 1u;
    bf16x8 a = *(const bf16x8*)(hnb + (size_t)(r0 + l16)*32 + half*8);
    float4 t4 = *(const float4*)(tau + r0 + half*4);
    float tm0 = t4.x - MARGIN, tm1 = t4.y - MARGIN,
          tm2 = t4.z - MARGIN, tm3 = t4.w - MARGIN;
    f32x4 zero = {0.f, 0.f, 0.f, 0.f};
    const int SPANW = N / 16;        // 512 cands per wave
    int jb0 = wave * SPANW;

#define APPB2(R, HA, HB)                                                     \
    {                                                                        \
      bool hA = (HA), hB = (HB);                                             \
      unsigned long long mrA = __ballot(hA);                                 \
      unsigned long long mrB = __ballot(hB);                                 \
      unsigned maskA = (unsigned)(mrA >> (16*half)) & 0xFFFFu;               \
      unsigned maskB = (unsigned)(mrB >> (16*half)) & 0xFFFFu;               \
      if (maskA | maskB) {                                                   \
        int rl = 4*half + (R);                                               \
        int pca = __popc(maskA);                                             \
        int base = 0;                                                        \
        if (l16 == 0) base = atomicAdd(&cntl[rl], pca + __popc(maskB));      \
        base = __shfl(base, gleader);                                        \
        if (hA) {                                                            \
          int p = base + __popc(maskA & below);                              \
          if (p < CAPL) hbuf[rl][p] = (unsigned short)(jbA + l16);           \
        }                                                                    \
        if (hB) {                                                            \
          int p = base + pca + __popc(maskB & below);                        \
          if (p < CAPL) hbuf[rl][p] = (unsigned short)(jbB + l16);           \
        }                                                                    \
      }                                                                      \
    }

#pragma unroll 2
    for (int jt = 0; jt < SPANW; jt += 32) {
      int jbA = jb0 + jt, jbB = jbA + 16;
      bf16x8 bA = *(const bf16x8*)(hnb + (size_t)(jbA + l16)*32 + half*8);
      bf16x8 bB = *(const bf16x8*)(hnb + (size_t)(jbB + l16)*32 + half*8);
      f32x4 dA = __builtin_amdgcn_mfma_f32_16x16x32_bf16(a, bA, zero, 0, 0, 0);
      f32x4 dB = __builtin_amdgcn_mfma_f32_16x16x32_bf16(a, bB, zero, 0, 0, 0);
      bool a0 = dA[0] >= tm0, a1 = dA[1] >= tm1, a2 = dA[2] >= tm2, a3 = dA[3] >= tm3;
      bool b0 = dB[0] >= tm0, b1 = dB[1] >= tm1, b2 = dB[2] >= tm2, b3 = dB[3] >= tm3;
      if (__any(a0 | a1 | a2 | a3 | b0 | b1 | b2 | b3)) {
        APPB2(0, a0, b0) APPB2(1, a1, b1) APPB2(2, a2, b2) APPB2(3, a3, b3)
      }
    }
#undef APPB2
  }
  __syncthreads();

  // ---- phase 3: exact fp32 top-6 from LDS hit list, wave per row ----
  {
    int row = r0 + wave;
    int n = min(cntl[wave], CAPL);
    float4 q[4];
#pragma unroll
    for (int m = 0; m < 4; ++m) q[m] = hn4[(size_t)row*4 + m];
    Top6 t; t6_init(t);
    for (int e = lane; e < n; e += 64) {
      int j = hbuf[wave][e];
      if (j != row) {
        float4 cv[4];
#pragma unroll
        for (int m = 0; m < 4; ++m) cv[m] = hn4[(size_t)j*4 + m];
        float sc = dot16_seq(q, cv);
        t6_insert(t, sc, j);
      }
    }
    float osum = 0.f;
    for (int sel = 0; sel < K; ++sel) {
      float cv; int ci;
      t6_best(t, cv, ci);
      float mv = cv; int mi = ci;
#pragma unroll
      for (int m = 1; m < 64; m <<= 1) {
        float ov = __shfl_xor(mv, m);
        int   oi = __shfl_xor(mi, m);
        if (ov > mv || (ov == mv && (unsigned)oi < (unsigned)mi)) { mv = ov; mi = oi; }
      }
      t6_consume(t, mi);
      if (lane == 0) {
        evals[row*K + sel] = mv;
        eidx [row*K + sel] = mi;
        osum += mv;
        atomicAdd(&insum[mi], mv);
        int pos = atomicAdd(&indeg[mi], 1);
        if (pos < CIN) {
          incol[(size_t)mi*CIN + pos] = (unsigned short)row;
          inval[(size_t)mi*CIN + pos] = mv;
        }
      }
    }
    if (lane == 0) ownsum[row] = osum;
  }
}

// ---- DOUT=32 layer: GCN + LN + ReLU + MLP residual, 2 rows/wave.
// SCALED: XWsrc already carries dinv_j -> per-edge coef is cc*v.
// Epilogue writes XWnext PRE-SCALED by dinv_row.
template<int DIN, int NEXTD, bool SCALED>
__global__ __launch_bounds__(256) void k_gpost32(
    const float* __restrict__ XWsrc,
    const int* __restrict__ eidx, const float* __restrict__ evals,
    const unsigned short* __restrict__ incol, const float* __restrict__ inval,
    const int* __restrict__ indeg,
    const float* __restrict__ ownsum, const float* __restrict__ insum,
    const float* __restrict__ gb, const float* __restrict__ lg, const float* __restrict__ lb,
    const float* __restrict__ hprev,
    const float* __restrict__ w0, const float* __restrict__ b0,
    const float* __restrict__ w1, const float* __restrict__ b1,
    const float* __restrict__ Wnext, float* __restrict__ XWnext,
    float* __restrict__ outp, int N) {
  __shared__ float hid[4][2][32];
  int tid = threadIdx.x;
  int lane = tid & 63, wslot = tid >> 6;
  int sub = lane >> 5, ol = lane & 31;
  int row = (blockIdx.x * 4 + wslot) * 2 + sub;

  float rs_i = 0.5f * (ownsum[row] + insum[row]);
  float rn_i = 1.f / (rs_i + 1e-8f);
  float di_i = rsqrtf(fmaxf(1.f + rs_i * rn_i, 1e-12f));
  float cc = 0.5f * di_i * rn_i;
  float acc = (SCALED ? di_i : di_i * di_i) * XWsrc[(size_t)row*32 + ol];
#pragma unroll
  for (int t = 0; t < K; ++t) {
    int j = eidx[row*K + t]; float v = evals[row*K + t];
    float cf;
    if constexpr (SCALED) cf = cc * v;
    else                  cf = cc * v * dinv_of(ownsum[j], insum[j]);
    acc = fmaf(cf, XWsrc[(size_t)j*32 + ol], acc);
  }
  int ne = min(indeg[row], CIN);
  for (int e = 0; e < ne; ++e) {
    int j = incol[(size_t)row*CIN + e]; float v = inval[(size_t)row*CIN + e];
    float cf;
    if constexpr (SCALED) cf = cc * v;
    else                  cf = cc * v * dinv_of(ownsum[j], insum[j]);
    acc = fmaf(cf, XWsrc[(size_t)j*32 + ol], acc);
  }
  float u0 = acc + gb[ol];
  float s = u0;
#pragma unroll
  for (int m = 1; m < 32; m <<= 1) s += __shfl_xor(s, m);
  float mean = s * (1.f/32.f);
  float d0 = u0 - mean;
  float vs = d0*d0;
#pragma unroll
  for (int m = 1; m < 32; m <<= 1) vs += __shfl_xor(vs, m);
  float rstd = rsqrtf(vs * (1.f/32.f) + 1e-5f);
  float t0 = fmaxf(d0*rstd*lg[ol] + lb[ol], 0.f);

  // MLP residual (per-wave LDS; same-wave lockstep -> no barrier)
  float hp[DIN];
#pragma unroll
  for (int d = 0; d < DIN; ++d) hp[d] = hprev[(size_t)row*DIN + d];
  float a = b0[ol];
#pragma unroll
  for (int d = 0; d < DIN; ++d) a = fmaf(hp[d], w0[d*32 + ol], a);
  hid[wslot][sub][ol] = fmaxf(a, 0.f);
  float o = b1[ol];
#pragma unroll
  for (int h = 0; h < 32; ++h) o = fmaf(hid[wslot][sub][h], w1[h*32 + ol], o);
  float hv = t0 + o;
  outp[(size_t)row*32 + ol] = hv;

  // epilogue: XWnext = dinv_row * (h @ Wnext)  (PRE-SCALED for next layer)
  hid[wslot][sub][ol] = hv;
#pragma unroll
  for (int k2 = 0; k2 < NEXTD/32; ++k2) {
    int oc = ol + 32*k2;
    float acc2 = 0.f;
#pragma unroll
    for (int d = 0; d < 32; ++d)
      acc2 = fmaf(hid[wslot][sub][d], Wnext[d*NEXTD + oc], acc2);
    XWnext[(size_t)row*NEXTD + oc] = di_i * acc2;
  }
}

// ---------------- final layer (DOUT=128): pre-scaled XW gather + LDS-staged w1 ----
__global__ __launch_bounds__(256) void k_gpost128(
    const float* __restrict__ XW,     // pre-scaled by dinv_j
    const int* __restrict__ eidx, const float* __restrict__ evals,
    const unsigned short* __restrict__ incol, const float* __restrict__ inval,
    const int* __restrict__ indeg,
    const float* __restrict__ ownsum, const float* __restrict__ insum,
    const float* __restrict__ b, const float* __restrict__ g, const float* __restrict__ bt,
    const float* __restrict__ hprev,
    const float* __restrict__ w0, const float* __restrict__ b0,
    const float* __restrict__ w1, const float* __restrict__ b1,
    float* __restrict__ out, int N) {
  __shared__ float hid_s[4][128];
  __shared__ float w1s[2048];          // 16 h-rows x 128 cols chunk (8 KB)
  int wslot = threadIdx.x >> 6;
  int row   = (blockIdx.x * blockDim.x + threadIdx.x) >> 6;
  int lane  = threadIdx.x & 63;
  int o0 = lane, o1 = lane + 64;

  float rs_i = 0.5f * (ownsum[row] + insum[row]);
  float rn_i = 1.f / (rs_i + 1e-8f);
  float di_i = rsqrtf(fmaxf(1.f + rs_i * rn_i, 1e-12f));
  float cc = 0.5f * di_i * rn_i;
  float acc0 = di_i * XW[(size_t)row*128 + o0];
  float acc1 = di_i * XW[(size_t)row*128 + o1];
#pragma unroll
  for (int t = 0; t < K; ++t) {
    int j = eidx[row*K + t];
    float cf = cc * evals[row*K + t];
    acc0 = fmaf(cf, XW[(size_t)j*128 + o0], acc0);
    acc1 = fmaf(cf, XW[(size_t)j*128 + o1], acc1);
  }
  int ne = min(indeg[row], CIN);
  for (int e = 0; e < ne; ++e) {
    int j = incol[(size_t)row*CIN + e];
    float cf = cc * inval[(size_t)row*CIN + e];
    acc0 = fmaf(cf, XW[(size_t)j*128 + o0], acc0);
    acc1 = fmaf(cf, XW[(size_t)j*128 + o1], acc1);
  }
  float u0 = acc0 + b[o0];
  float u1 = acc1 + b[o1];

  float s = u0 + u1;
#pragma unroll
  for (int m = 1; m < 64; m <<= 1) s += __shfl_xor(s, m);
  float mean = s * (1.f/128.f);
  float d0 = u0 - mean, d1 = u1 - mean;
  float vs = d0*d0 + d1*d1;
#pragma unroll
  for (int m = 1; m < 64; m <<= 1) vs += __shfl_xor(vs, m);
  float rstd = rsqrtf(vs * (1.f/128.f) + 1e-5f);
  float t0 = fmaxf(d0*rstd*g[o0] + bt[o0], 0.f);
  float t1 = fmaxf(d1*rstd*g[o1] + bt[o1], 0.f);

  float hp[32];
#pragma unroll
  for (int d = 0; d < 32; ++d) hp[d] = hprev[(size_t)row*32 + d];
  {
    float a = b0[o0];
#pragma unroll
    for (int d = 0; d < 32; ++d) a = fmaf(hp[d], w0[d*128 + o0], a);
    hid_s[wslot][o0] = fmaxf(a, 0.f);
    float a1 = b0[o1];
#pragma unroll
    for (int d = 0; d < 32; ++d) a1 = fmaf(hp[d], w0[d*128 + o1], a1);
    hid_s[wslot][o1] = fmaxf(a1, 0.f);
  }

  // out = hid @ w1 with w1 staged through LDS in 8 chunks of 16 rows.
  float r0=0.f, r1=0.f, r2=0.f, r3=0.f, q0=0.f, q1=0.f, q2=0.f, q3=0.f;
  for (int c = 0; c < 8; ++c) {
    __syncthreads();
    {
      const float4* src = (const float4*)(w1 + c*2048);
      float4* dst = (float4*)w1s;
      dst[threadIdx.x]       = src[threadIdx.x];
      dst[threadIdx.x + 256] = src[threadIdx.x + 256];
    }
    __syncthreads();
    int hb = c*16;
#pragma unroll
    for (int hh = 0; hh < 16; hh += 4) {
      float h0 = hid_s[wslot][hb+hh+0], h1 = hid_s[wslot][hb+hh+1],
            h2 = hid_s[wslot][hb+hh+2], h3 = hid_s[wslot][hb+hh+3];
      r0 = fmaf(h0, w1s[(hh+0)*128 + o0], r0); q0 = fmaf(h0, w1s[(hh+0)*128 + o1], q0);
      r1 = fmaf(h1, w1s[(hh+1)*128 + o0], r1); q1 = fmaf(h1, w1s[(hh+1)*128 + o1], q1);
      r2 = fmaf(h2, w1s[(hh+2)*128 + o0], r2); q2 = fmaf(h2, w1s[(hh+2)*128 + o1], q2);
      r3 = fmaf(h3, w1s[(hh+3)*128 + o0], r3); q3 = fmaf(h3, w1s[(hh+3)*128 + o1], q3);
    }
  }
  out[(size_t)row*128 + o0] = t0 + b1[o0] + ((r0 + r1) + (r2 + r3));
  out[(size_t)row*128 + o1] = t1 + b1[o1] + ((q0 + q1) + (q2 + q3));
}

extern "C" void kernel_launch(void* const* d_in, const int* in_sizes, int n_in,
                              void* d_out, int out_size, void* d_ws, size_t ws_size,
                              hipStream_t stream) {
  const float* x    = (const float*)d_in[0];
  const float* Wp   = (const float*)d_in[1];
  const float* bp   = (const float*)d_in[2];
  const float* gw0  = (const float*)d_in[3];
  const float* gb0  = (const float*)d_in[4];
  const float* gw1  = (const float*)d_in[5];
  const float* gb1  = (const float*)d_in[6];
  const float* gw2  = (const float*)d_in[7];
  const float* gb2  = (const float*)d_in[8];
  const float* lg0  = (const float*)d_in[9];
  const float* lb0  = (const float*)d_in[10];
  const float* lg1  = (const float*)d_in[11];
  const float* lb1  = (const float*)d_in[12];
  const float* lg2  = (const float*)d_in[13];
  const float* lb2  = (const float*)d_in[14];
  const float* riw0 = (const float*)d_in[15];
  const float* rib0 = (const float*)d_in[16];
  const float* riw1 = (const float*)d_in[17];
  const float* rib1 = (const float*)d_in[18];
  const float* rhw0 = (const float*)d_in[19];
  const float* rhb0 = (const float*)d_in[20];
  const float* rhw1 = (const float*)d_in[21];
  const float* rhb1 = (const float*)d_in[22];
  const float* row0 = (const float*)d_in[23];
  const float* rob0 = (const float*)d_in[24];
  const float* row1 = (const float*)d_in[25];
  const float* rob1 = (const float*)d_in[26];
  int N = in_sizes[0] / D_IN;   // 8192
  float* out = (float*)d_out;

  char* ws = (char*)d_ws;
  size_t off = 0;
  auto alloc = [&](size_t bytes) -> void* {
    void* p = ws + off;
    off += (bytes + 255) & ~(size_t)255;
    return p;
  };
  float* hn      = (float*)alloc((size_t)N * HP * 4);
  float* evals   = (float*)alloc((size_t)N * K * 4);
  int*   eidx    = (int*)  alloc((size_t)N * K * 4);
  float* ownsum  = (float*)alloc((size_t)N * 4);
  float* insum   = (float*)alloc((size_t)N * 4);
  int*   indeg   = (int*)  alloc((size_t)N * 4);
  float* XWa     = (float*)alloc((size_t)N * 128 * 4);
  float* XWb     = (float*)alloc((size_t)N * 32 * 4);
  float* h1      = (float*)alloc((size_t)N * 32 * 4);
  float* h2      = (float*)alloc((size_t)N * 32 * 4);
  float* tau     = (float*)alloc((size_t)N * 4);
  short* hnb     = (short*)alloc((size_t)N * 32 * 2);
  unsigned short* incol = (unsigned short*)alloc((size_t)N * CIN * 2);
  float* inval   = (float*)alloc((size_t)N * CIN * 4);
  (void)ws_size; (void)n_in; (void)out_size;

  const int B = 256;
  hipLaunchKernelGGL(k_proj, dim3((N + B - 1) / B), dim3(B), 0, stream,
                     x, Wp, bp, gw0, hn, hnb, XWa, insum, indeg, N);
  hipLaunchKernelGGL(k_thresh, dim3(N / 4), dim3(B), 0, stream, hn, tau, N);
  hipLaunchKernelGGL(k_scan23, dim3(N / 16), dim3(1024), 0, stream,
                     hn, hnb, tau, evals, eidx, ownsum, insum, indeg, incol, inval, N);

  // layer 0: XWa unscaled -> h1; epilogue XWb = dinv * (h1 @ gw1)
  hipLaunchKernelGGL((k_gpost32<20, 32, false>), dim3(N / 8), dim3(B), 0, stream,
                     XWa, eidx, evals, incol, inval, indeg, ownsum, insum,
                     gb0, lg0, lb0, x, riw0, rib0, riw1, rib1, gw1, XWb, h1, N);
  // layer 1: XWb pre-scaled -> h2; epilogue XWa = dinv * (h2 @ gw2)
  hipLaunchKernelGGL((k_gpost32<32, 128, true>), dim3(N / 8), dim3(B), 0, stream,
                     XWb, eidx, evals, incol, inval, indeg, ownsum, insum,
                     gb1, lg1, lb1, h1, rhw0, rhb0, rhw1, rhb1, gw2, XWa, h2, N);
  // layer 2: XWa pre-scaled -> out
  hipLaunchKernelGGL(k_gpost128, dim3(N / 4), dim3(B), 0, stream,
                     XWa, eidx, evals, incol, inval, indeg, ownsum, insum,
                     gb2, lg2, lb2, h2, row0, rob0, row1, rob1, out, N);
}